// Round 17
// baseline (283.353 us; speedup 1.0000x reference)
//
#include <hip/hip_runtime.h>
#include <math.h>

#define NHEADS 32
#define D_INNER 2048
#define CONV_DIM 2304
#define D_IN_PROJ 4384
#define POOL_N 50
#define BT 2048

typedef __attribute__((ext_vector_type(8))) short short8;
typedef __attribute__((ext_vector_type(4))) float f32x4;

__device__ __forceinline__ float sigmoidf_(float x){ return 1.f/(1.f+expf(-x)); }
__device__ __forceinline__ ushort f2bf(float f){
  union{float f; unsigned u;} v; v.f=f;
  unsigned r = v.u + 0x7fffu + ((v.u>>16)&1u);
  return (ushort)(r>>16);
}
__device__ __forceinline__ void gload16(const void* g, void* l){
  __builtin_amdgcn_global_load_lds(
    (const __attribute__((address_space(1))) unsigned int*)g,
    (__attribute__((address_space(3))) unsigned int*)l, 16, 0, 0);
}

// ---------------- RMSNorm on x (D=1024) -> bf16 ----------------
__global__ __launch_bounds__(256) void k_rmsnorm_x(const float* __restrict__ x, const float* __restrict__ w, ushort* __restrict__ xn){
  int r = blockIdx.x;
  const float* xr = x + (size_t)r*1024;
  float v[4]; float ss=0.f;
  for(int i=0;i<4;i++){ v[i]=xr[threadIdx.x+i*256]; ss+=v[i]*v[i]; }
  __shared__ float red[4];
  for(int off=32;off;off>>=1) ss += __shfl_down(ss,off,64);
  int wid=threadIdx.x>>6, lane=threadIdx.x&63;
  if(lane==0) red[wid]=ss;
  __syncthreads();
  float tot=red[0]+red[1]+red[2]+red[3];
  float rs=rsqrtf(tot*(1.f/1024.f)+1e-5f);
  for(int i=0;i<4;i++){ int c=threadIdx.x+i*256; xn[(size_t)r*1024+c]=f2bf(v[i]*rs*w[c]); }
}

// ---------------- transpose + cvt: src f32 [R][C] -> dst bf16 [C][R] ----------------
__global__ __launch_bounds__(256) void k_transpose_cvt(const float* __restrict__ src, ushort* __restrict__ dst, int R, int C){
  __shared__ float tile[32][33];
  int c0 = blockIdx.x*32, r0 = blockIdx.y*32;
  int tx = threadIdx.x&31, ty = threadIdx.x>>5;
  for(int i=0;i<4;i++){ int r = r0+ty+i*8; tile[ty+i*8][tx] = src[(size_t)r*C + c0+tx]; }
  __syncthreads();
  for(int i=0;i<4;i++){ int c = c0+ty+i*8; dst[(size_t)c*R + r0+tx] = f2bf(tile[tx][ty+i*8]); }
}

// ---------------- bf16 MFMA GEMM (BM=128): BK=32, 4-buffer LDS, depth-3 counted vmcnt, XOR-swizzled ----------------
// K must be a multiple of 32.
__global__ __launch_bounds__(256) void gemm_bf16(const ushort* __restrict__ A, const ushort* __restrict__ Bt,
    float* __restrict__ C, ushort* __restrict__ Cb, int M, int N, int K, int act, int nbx){
  __shared__ __align__(16) ushort As[4][128*32];
  __shared__ __align__(16) ushort Bs[4][128*32];
  int wg = blockIdx.x, nwg = gridDim.x;
  if((nwg & 7)==0){ int cpx = nwg>>3; wg = (wg&7)*cpx + (wg>>3); }
  int bx = wg % nbx, by = wg / nbx;
  int n0 = bx*128, m0 = by*128;
  int tid = threadIdx.x;
  int lane = tid&63, w = tid>>6;
  int wr = (w>>1)*64, wc = (w&1)*64;
  f32x4 acc[4][4];
  for(int i=0;i<4;i++)for(int j=0;j<4;j++)acc[i][j]=(f32x4){0.f,0.f,0.f,0.f};
  // staging: chunk id e = c*256 + w*64 + lane; row = e>>2 = c*64 + tid>>2; col16 = lane&3 = tid&3.
  // pre-swizzled source chunk: col16s = (tid&3) ^ ((tid>>2)&3)
  int col16s = (tid&3) ^ ((tid>>2)&3);
  int r0t = tid>>2;
  const char* AG[2]; const char* BG[2];
  #pragma unroll
  for(int c=0;c<2;c++){
    int r = r0t + c*64;
    AG[c] = (const char*)(A + (size_t)(m0+r)*K + col16s*8);
    int br = n0 + r;
    BG[c] = (const char*)(Bt + (size_t)((br<N)?br:0)*K + col16s*8);
  }
  int nk = K >> 5;
  int fr = lane&15, fq = lane>>4;
  // prologue: stage steps 0,1,2 into buffers 0,1,2 (12 loads/thread in flight)
  #pragma unroll
  for(int t=0;t<3;t++){
    #pragma unroll
    for(int c=0;c<2;c++){
      gload16(AG[c]+(size_t)t*64, (char*)As[t] + (c*256 + w*64)*16);
      gload16(BG[c]+(size_t)t*64, (char*)Bs[t] + (c*256 + w*64)*16);
    }
  }
  for(int ks=0; ks<nk; ks++){
    int cur = ks & 3;
    if(ks+3 < nk){
      size_t kb = (size_t)(ks+3)*64;
      int nb = (ks+3)&3;
      #pragma unroll
      for(int c=0;c<2;c++){
        gload16(AG[c]+kb, (char*)As[nb] + (c*256 + w*64)*16);
        gload16(BG[c]+kb, (char*)Bs[nb] + (c*256 + w*64)*16);
      }
      asm volatile("s_waitcnt vmcnt(12)" ::: "memory");
    } else if(ks+2 < nk){
      asm volatile("s_waitcnt vmcnt(8)" ::: "memory");
    } else if(ks+1 < nk){
      asm volatile("s_waitcnt vmcnt(4)" ::: "memory");
    } else {
      asm volatile("s_waitcnt vmcnt(0)" ::: "memory");
    }
    __builtin_amdgcn_s_barrier();
    __builtin_amdgcn_sched_barrier(0);
    short8 af[4], bfr[4];
    #pragma unroll
    for(int i=0;i<4;i++){
      int rl = wr+i*16+fr;
      int off = (rl<<6) + (((fq ^ (rl&3)))<<4);
      af[i] = *(const short8*)((char*)As[cur] + off);
    }
    #pragma unroll
    for(int j=0;j<4;j++){
      int rl = wc+j*16+fr;
      int off = (rl<<6) + (((fq ^ (rl&3)))<<4);
      bfr[j] = *(const short8*)((char*)Bs[cur] + off);
    }
    #pragma unroll
    for(int i=0;i<4;i++)
      #pragma unroll
      for(int j=0;j<4;j++)
        acc[i][j] = __builtin_amdgcn_mfma_f32_16x16x32_bf16(af[i], bfr[j], acc[i][j], 0,0,0);
    asm volatile("s_waitcnt lgkmcnt(0)" ::: "memory");
    __builtin_amdgcn_sched_barrier(0);
    __builtin_amdgcn_s_barrier();
  }
  int rbase = m0 + wr + fq*4;
  for(int i=0;i<4;i++){
    for(int j=0;j<4;j++){
      int col = n0 + wc + j*16 + fr;
      if(col < N){
        for(int r=0;r<4;r++){
          float v = acc[i][j][r];
          if(act) v = fmaxf(v,0.f);
          size_t idx = (size_t)(rbase + i*16 + r)*N + col;
          C[idx] = v;
          if(Cb) Cb[idx] = f2bf(v);
        }
      }
    }
  }
}

// ---------------- bf16 MFMA GEMM (BM=64): for M=2048,N<=1024 shapes (grid doubling) ----------------
__global__ __launch_bounds__(256) void gemm_bf16_64(const ushort* __restrict__ A, const ushort* __restrict__ Bt,
    float* __restrict__ C, ushort* __restrict__ Cb, int M, int N, int K, int act, int nbx){
  __shared__ __align__(16) ushort As[2][64*64];
  __shared__ __align__(16) ushort Bs[2][128*64];
  int wg = blockIdx.x, nwg = gridDim.x;
  if((nwg & 7)==0){ int cpx = nwg>>3; wg = (wg&7)*cpx + (wg>>3); }
  int bx = wg % nbx, by = wg / nbx;
  int n0 = bx*128, m0 = by*64;
  int tid = threadIdx.x;
  int lane = tid&63, w = tid>>6;
  f32x4 acc[4][2];
  for(int i=0;i<4;i++)for(int j=0;j<2;j++)acc[i][j]=(f32x4){0.f,0.f,0.f,0.f};
  int col16s = (tid&7) ^ ((tid>>3)&7);
  int r0t = tid>>3;
  const char* AG[2]; const char* BG[4];
  #pragma unroll
  for(int c=0;c<2;c++){
    int r = r0t + c*32;
    AG[c] = (const char*)(A + (size_t)(m0+r)*K + col16s*8);
  }
  #pragma unroll
  for(int c=0;c<4;c++){
    int br = n0 + r0t + c*32;
    BG[c] = (const char*)(Bt + (size_t)((br<N)?br:0)*K + col16s*8);
  }
  int nk = K >> 6;
  int fr = lane&15, fq = lane>>4;
  {
    #pragma unroll
    for(int c=0;c<2;c++) gload16(AG[c], (char*)As[0] + (c*256 + w*64)*16);
    #pragma unroll
    for(int c=0;c<4;c++) gload16(BG[c], (char*)Bs[0] + (c*256 + w*64)*16);
  }
  for(int ks=0; ks<nk; ks++){
    int cur = ks&1;
    if(ks+1 < nk){
      size_t kb = (size_t)(ks+1)*128;
      #pragma unroll
      for(int c=0;c<2;c++) gload16(AG[c]+kb, (char*)As[cur^1] + (c*256 + w*64)*16);
      #pragma unroll
      for(int c=0;c<4;c++) gload16(BG[c]+kb, (char*)Bs[cur^1] + (c*256 + w*64)*16);
      asm volatile("s_waitcnt vmcnt(6)" ::: "memory");
    } else {
      asm volatile("s_waitcnt vmcnt(0)" ::: "memory");
    }
    __builtin_amdgcn_s_barrier();
    __builtin_amdgcn_sched_barrier(0);
    #pragma unroll
    for(int kk=0;kk<2;kk++){
      short8 af[4], bfr[2];
      #pragma unroll
      for(int i=0;i<4;i++){
        int rl = i*16+fr;
        int off = ((rl<<7) + (kk<<6) + (fq<<4)) ^ ((rl&7)<<4);
        af[i] = *(const short8*)((char*)As[cur] + off);
      }
      #pragma unroll
      for(int j=0;j<2;j++){
        int rl = w*32+j*16+fr;
        int off = ((rl<<7) + (kk<<6) + (fq<<4)) ^ ((rl&7)<<4);
        bfr[j] = *(const short8*)((char*)Bs[cur] + off);
      }
      #pragma unroll
      for(int i=0;i<4;i++)
        #pragma unroll
        for(int j=0;j<2;j++)
          acc[i][j] = __builtin_amdgcn_mfma_f32_16x16x32_bf16(af[i], bfr[j], acc[i][j], 0,0,0);
    }
    asm volatile("s_waitcnt lgkmcnt(0)" ::: "memory");
    __builtin_amdgcn_sched_barrier(0);
    __builtin_amdgcn_s_barrier();
  }
  int rbase = m0 + fq*4;
  for(int i=0;i<4;i++){
    for(int j=0;j<2;j++){
      int col = n0 + w*32 + j*16 + fr;
      if(col < N){
        for(int r=0;r<4;r++){
          float v = acc[i][j][r];
          if(act) v = fmaxf(v,0.f);
          size_t idx = (size_t)(rbase + i*16 + r)*N + col;
          C[idx] = v;
          if(Cb) Cb[idx] = f2bf(v);
        }
      }
    }
  }
}

// ---------------- gate GEMM (BM=64): A=[youtb|retrb] split at k=1024, fused final epilogue ----------------
__global__ __launch_bounds__(256) void gemm_gate64(const ushort* __restrict__ Ay, const ushort* __restrict__ Ar,
    const ushort* __restrict__ Bt, const float* __restrict__ x, const float* __restrict__ yout,
    const float* __restrict__ retr, const float* __restrict__ condf, float* __restrict__ out){
  __shared__ __align__(16) ushort As[2][64*64];
  __shared__ __align__(16) ushort Bs[2][128*64];
  const int nbx = 8;
  int wg = blockIdx.x, nwg = gridDim.x;
  if((nwg & 7)==0){ int cpx = nwg>>3; wg = (wg&7)*cpx + (wg>>3); }
  int bx = wg % nbx, by = wg / nbx;
  int n0 = bx*128, m0 = by*64;
  int tid = threadIdx.x;
  int lane = tid&63, w = tid>>6;
  f32x4 acc[4][2];
  for(int i=0;i<4;i++)for(int j=0;j<2;j++)acc[i][j]=(f32x4){0.f,0.f,0.f,0.f};
  int col16s = (tid&7) ^ ((tid>>3)&7);
  int r0t = tid>>3;
  const char* AGy[2]; const char* AGr[2]; const char* BG[4];
  #pragma unroll
  for(int c=0;c<2;c++){
    int r = r0t + c*32;
    AGy[c] = (const char*)(Ay + (size_t)(m0+r)*1024 + col16s*8);
    AGr[c] = (const char*)(Ar + (size_t)(m0+r)*1024 + col16s*8);
  }
  #pragma unroll
  for(int c=0;c<4;c++){
    int br = n0 + r0t + c*32;
    BG[c] = (const char*)(Bt + (size_t)br*2048 + col16s*8);
  }
  const int nk = 32;
  int fr = lane&15, fq = lane>>4;
  {
    #pragma unroll
    for(int c=0;c<2;c++) gload16(AGy[c], (char*)As[0] + (c*256 + w*64)*16);
    #pragma unroll
    for(int c=0;c<4;c++) gload16(BG[c],  (char*)Bs[0] + (c*256 + w*64)*16);
  }
  for(int ks=0; ks<nk; ks++){
    int cur = ks&1;
    if(ks+1 < nk){
      int t = ks+1;
      size_t kbA = (size_t)((t<16)? t : t-16)*128;
      size_t kbB = (size_t)t*128;
      #pragma unroll
      for(int c=0;c<2;c++){
        const char* asrc = (t<16) ? (AGy[c]+kbA) : (AGr[c]+kbA);
        gload16(asrc, (char*)As[cur^1] + (c*256 + w*64)*16);
      }
      #pragma unroll
      for(int c=0;c<4;c++) gload16(BG[c]+kbB, (char*)Bs[cur^1] + (c*256 + w*64)*16);
      asm volatile("s_waitcnt vmcnt(6)" ::: "memory");
    } else {
      asm volatile("s_waitcnt vmcnt(0)" ::: "memory");
    }
    __builtin_amdgcn_s_barrier();
    __builtin_amdgcn_sched_barrier(0);
    #pragma unroll
    for(int kk=0;kk<2;kk++){
      short8 af[4], bfr[2];
      #pragma unroll
      for(int i=0;i<4;i++){
        int rl = i*16+fr;
        int off = ((rl<<7) + (kk<<6) + (fq<<4)) ^ ((rl&7)<<4);
        af[i] = *(const short8*)((char*)As[cur] + off);
      }
      #pragma unroll
      for(int j=0;j<2;j++){
        int rl = w*32+j*16+fr;
        int off = ((rl<<7) + (kk<<6) + (fq<<4)) ^ ((rl&7)<<4);
        bfr[j] = *(const short8*)((char*)Bs[cur] + off);
      }
      #pragma unroll
      for(int i=0;i<4;i++)
        #pragma unroll
        for(int j=0;j<2;j++)
          acc[i][j] = __builtin_amdgcn_mfma_f32_16x16x32_bf16(af[i], bfr[j], acc[i][j], 0,0,0);
    }
    asm volatile("s_waitcnt lgkmcnt(0)" ::: "memory");
    __builtin_amdgcn_sched_barrier(0);
    __builtin_amdgcn_s_barrier();
  }
  float cond = condf[0];
  int rbase = m0 + fq*4;
  for(int i=0;i<4;i++){
    for(int j=0;j<2;j++){
      int col = n0 + w*32 + j*16 + fr;
      for(int r=0;r<4;r++){
        size_t idx = (size_t)(rbase + i*16 + r)*1024 + col;
        float gv = sigmoidf_(acc[i][j][r]);
        out[idx] = x[idx] + yout[idx] + cond*gv*retr[idx];
      }
    }
  }
}

// ---------------- dt = softplus(zxb[:, -32:] + bias) ----------------
__global__ void k_dt(const float* __restrict__ zxb, const float* __restrict__ dt_bias, float* __restrict__ dtb){
  int o = blockIdx.x*256+threadIdx.x; // 2048*32
  int r = o>>5, h = o&31;
  float v = zxb[(size_t)r*D_IN_PROJ + 4352 + h] + dt_bias[h];
  dtb[o] = (v>20.f) ? v : log1pf(expf(v));
}

// ---------------- causal depthwise conv (k=4) + silu, 4 channels/thread ----------------
__global__ void k_conv4(const float* __restrict__ zxb, const float* __restrict__ cw, const float* __restrict__ cb, float* __restrict__ xbc){
  int o = blockIdx.x*256+threadIdx.x; // 2048*576
  if(o >= 2048*576) return;
  int ch4 = (o % 576)*4; int rt = o / 576;
  int b = rt>>10, t = rt&1023;
  float a[4];
  { float4 cbv = *(const float4*)(cb + ch4); a[0]=cbv.x; a[1]=cbv.y; a[2]=cbv.z; a[3]=cbv.w; }
  float cwa[4][4];
  for(int c2=0;c2<4;c2++){
    float4 v = *(const float4*)(cw + (ch4+c2)*4);
    cwa[c2][0]=v.x; cwa[c2][1]=v.y; cwa[c2][2]=v.z; cwa[c2][3]=v.w;
  }
  for(int k=0;k<4;k++){
    int tt = t-3+k;
    if(tt>=0){
      float4 v = *(const float4*)(zxb + (size_t)(b*1024+tt)*D_IN_PROJ + 2048 + ch4);
      a[0] += v.x*cwa[0][k]; a[1] += v.y*cwa[1][k];
      a[2] += v.z*cwa[2][k]; a[3] += v.w*cwa[3][k];
    }
  }
  float4 o4;
  o4.x = a[0]*sigmoidf_(a[0]); o4.y = a[1]*sigmoidf_(a[1]);
  o4.z = a[2]*sigmoidf_(a[2]); o4.w = a[3]*sigmoidf_(a[3]);
  *(float4*)(xbc + (size_t)rt*CONV_DIM + ch4) = o4;
}

// ---------------- G^T per (b,c): Gt[s*256+l] = dot(C[l], B[s]) ----------------
__global__ __launch_bounds__(256) void k_gt(const float* __restrict__ xbc, float* __restrict__ Gt){
  int bc = blockIdx.x >> 8;
  int tile = blockIdx.x & 255;
  int l0 = (tile>>4)<<4, s0 = (tile&15)<<4;
  int b = bc>>2, c = bc&3;
  int row0 = b*1024 + c*256;
  __shared__ float Cs[16][130], Bs2[16][130];
  int tid = threadIdx.x;
  for(int i=0;i<8;i++){ int e=tid+i*256; int rr=e>>7, n=e&127;
    Cs[rr][n]  = xbc[(size_t)(row0+l0+rr)*CONV_DIM + 2176 + n];
    Bs2[rr][n] = xbc[(size_t)(row0+s0+rr)*CONV_DIM + 2048 + n];
  }
  __syncthreads();
  int tx = tid&15, ty = tid>>4;
  float acc=0.f;
  for(int n=0;n<128;n++) acc += Cs[tx][n]*Bs2[ty][n];
  Gt[(size_t)bc*65536 + (size_t)(s0+ty)*256 + (l0+tx)] = acc;
}

// ---------------- SSD per (b,c,h): 512 threads, wave-specialized ----------------
__global__ __launch_bounds__(512) void k_ssd1w(const float* __restrict__ xbc, const float* __restrict__ dtb,
    const float* __restrict__ A_log, const float* __restrict__ Gt,
    float* __restrict__ ybuf, float* __restrict__ states, float* __restrict__ csb, float* __restrict__ sdA){
  int blk = blockIdx.x;      // (b*4+c)*32+h
  int bc = blk>>5, h = blk&31;
  int b = bc>>2, c = bc&3;
  int row0 = b*1024 + c*256;
  int tid = threadIdx.x;
  __shared__ float cs[256];
  __shared__ float dts[256];
  __shared__ float dec[256];
  __shared__ __align__(16) ushort xdT[64*256];
  __shared__ __align__(16) ushort Mw[4*64*32];
  __shared__ __align__(16) ushort Bw[4*32*256];
  float Ah = -expf(A_log[h]);
  if(tid < 256){
    float dtv = dtb[(size_t)(row0+tid)*32 + h];
    dts[tid] = dtv;
    cs[tid] = dtv*Ah;
  }
  __syncthreads();
  for(int o=1;o<256;o<<=1){
    float add = 0.f;
    if(tid<256 && tid>=o) add = cs[tid-o];
    __syncthreads();
    if(tid<256) cs[tid] += add;
    __syncthreads();
  }
  float cslast = cs[255];
  if(tid < 256){
    float csl = cs[tid];
    csb[blk*256+tid] = csl;
    dec[tid] = expf(cslast - csl);
    if(tid==0) sdA[blk] = cslast;
  }
  {
    int p = tid&63, g = tid>>6;
    for(int i=0;i<32;i++){
      int l = g + 8*i;
      float v = xbc[(size_t)(row0+l)*CONV_DIM + h*64 + p] * dts[l];
      int off = ((p<<9) + (l<<1)) ^ ((p&7)<<4);
      *(ushort*)((char*)xdT + off) = f2bf(v);
    }
  }
  __syncthreads();

  int w = tid>>6, lane = tid&63;
  int fr = lane&15, fq = lane>>4;
  const float* gt = Gt + (size_t)bc*65536;
  if(w < 4){
    int rowl = w*64 + lane;
    float csl_w = cs[rowl];
    f32x4 accY[4][4];
    for(int i=0;i<4;i++)for(int j=0;j<4;j++)accY[i][j]=(f32x4){0.f,0.f,0.f,0.f};
    int nk = 2*(w+1);
    for(int ks=0; ks<nk; ks++){
      int s0 = ks*32;
      float cs_s0 = cs[s0];
      float ev = expf(cs_s0 - cs[s0 + (lane&31)]);
      float el = expf(csl_w - cs_s0);
      for(int j=0;j<4;j++){
        short8 mp;
        for(int k=0;k<8;k++){
          int s2 = j*8+k;
          int s = s0 + s2;
          float gv = gt[(size_t)s*256 + rowl];
          float esv = __shfl(ev, s2, 64);
          float m = (s <= rowl) ? gv*el*esv : 0.f;
          mp[k] = (short)f2bf(m);
        }
        int off = (w<<12) + ((((lane)<<6) + (j<<4)) ^ ((lane&7)<<4));
        *(short8*)((char*)Mw + off) = mp;
      }
      asm volatile("s_waitcnt lgkmcnt(0)" ::: "memory");
      __builtin_amdgcn_sched_barrier(0);
      short8 af[4], bv4[4];
      for(int i=0;i<4;i++){
        int lp = i*16 + fr;
        int off = (w<<12) + (((lp<<6) + (fq<<4)) ^ ((lp&7)<<4));
        af[i] = *(const short8*)((char*)Mw + off);
      }
      for(int j=0;j<4;j++){
        int p = j*16 + fr;
        int off = ((p<<9) + ((s0 + fq*8)<<1)) ^ ((p&7)<<4);
        bv4[j] = *(const short8*)((char*)xdT + off);
      }
      for(int i=0;i<4;i++)
        for(int j=0;j<4;j++)
          accY[i][j] = __builtin_amdgcn_mfma_f32_16x16x32_bf16(af[i], bv4[j], accY[i][j], 0,0,0);
      asm volatile("" ::: "memory");
    }
    for(int i=0;i<4;i++){
      int l = 64*w + i*16 + fq*4;
      for(int j=0;j<4;j++){
        int p = j*16 + fr;
        for(int r=0;r<4;r++)
          ybuf[(size_t)(row0+l+r)*2048 + h*64 + p] = accY[i][j][r];
      }
    }
  } else {
    int sw = w-4, nbase = sw*32;
    {
      int nn = lane&31, half = lane>>5;
      for(int i=0;i<128;i++){
        int l = half + 2*i;
        float v = xbc[(size_t)(row0+l)*CONV_DIM + 2048 + nbase + nn] * dec[l];
        int off = (sw<<14) + (((nn<<9) + (l<<1)) ^ ((nn&7)<<4));
        *(ushort*)((char*)Bw + off) = f2bf(v);
      }
    }
    asm volatile("s_waitcnt lgkmcnt(0)" ::: "memory");
    __builtin_amdgcn_sched_barrier(0);
    f32x4 accS[4][2];
    for(int i=0;i<4;i++)for(int j=0;j<2;j++)accS[i][j]=(f32x4){0.f,0.f,0.f,0.f};
    for(int ks=0;ks<8;ks++){
      int l0 = ks*32;
      short8 aS[4], bS[2];
      for(int i=0;i<4;i++){
        int p = i*16 + fr;
        int off = ((p<<9) + ((l0+fq*8)<<1)) ^ ((p&7)<<4);
        aS[i] = *(const short8*)((char*)xdT + off);
      }
      for(int j=0;j<2;j++){
        int nn = j*16 + fr;
        int off = (sw<<14) + (((nn<<9) + ((l0+fq*8)<<1)) ^ ((nn&7)<<4));
        bS[j] = *(const short8*)((char*)Bw + off);
      }
      for(int i=0;i<4;i++)
        for(int j=0;j<2;j++)
          accS[i][j] = __builtin_amdgcn_mfma_f32_16x16x32_bf16(aS[i], bS[j], accS[i][j], 0,0,0);
    }
    for(int i=0;i<4;i++){
      int p = i*16 + fq*4;
      for(int j=0;j<2;j++){
        int n = nbase + j*16 + fr;
        for(int r=0;r<4;r++)
          states[(size_t)blk*8192 + (size_t)(p+r)*128 + n] = accS[i][j][r];
      }
    }
  }
}

// ---------------- chunk scan over c=0..3 ----------------
__global__ __launch_bounds__(256) void k_ssd2(const float* __restrict__ states, const float* __restrict__ sdA, float* __restrict__ prevb){
  int idx = blockIdx.x*256 + threadIdx.x;
  int e = idx & 8191;
  int h = (idx >> 13) & 31;
  int b = idx >> 18;
  float run = 0.f;
  for(int c=0;c<4;c++){
    int sblk = (b*4+c)*32 + h;
    size_t base = (size_t)sblk*8192 + e;
    prevb[base] = run;
    run = (run + states[base]) * expf(sdA[sblk]);
  }
}

// ---------------- y_off = C @ prev^T via MFMA; += xs*D into ybuf ----------------
__global__ __launch_bounds__(256) void k_ssd3m(const float* __restrict__ xbc, const float* __restrict__ csb,
    const float* __restrict__ prevb, const float* __restrict__ Dp, float* __restrict__ ybuf){
  int blk = blockIdx.x; int bc = blk>>5, h = blk&31; int b=bc>>2, c=bc&3;
  int row0 = b*1024+c*256;
  int tid = threadIdx.x;
  __shared__ __align__(16) ushort Cs[256*128];
  __shared__ __align__(16) ushort Ps[64*128];
  __shared__ float cse[256];
  for(int i=0;i<128;i++){
    int id = tid + i*256;
    int n = id & 127, l = id >> 7;
    float v = xbc[(size_t)(row0+l)*CONV_DIM + 2176 + n];
    int off = ((l<<8) + (n<<1)) ^ ((l&7)<<4);
    *(ushort*)((char*)Cs + off) = f2bf(v);
  }
  for(int i=0;i<32;i++){
    int id = tid + i*256;
    int n = id & 127, p = id >> 7;
    float v = prevb[(size_t)blk*8192 + id];
    int off = ((p<<8) + (n<<1)) ^ ((p&7)<<4);
    *(ushort*)((char*)Ps + off) = f2bf(v);
  }
  cse[tid] = expf(csb[blk*256+tid]);
  __syncthreads();
  int w=tid>>6, lane=tid&63, fr=lane&15, fq=lane>>4;
  f32x4 acc[4][4];
  for(int i=0;i<4;i++)for(int j=0;j<4;j++)acc[i][j]=(f32x4){0.f,0.f,0.f,0.f};
  for(int ks=0;ks<4;ks++){
    int n0 = ks*32;
    short8 af[4], bf_[4];
    for(int i=0;i<4;i++){
      int l = w*64 + i*16 + fr;
      int off = ((l<<8) + ((n0+fq*8)<<1)) ^ ((l&7)<<4);
      af[i] = *(const short8*)((char*)Cs + off);
    }
    for(int j=0;j<4;j++){
      int p = j*16 + fr;
      int off = ((p<<8) + ((n0+fq*8)<<1)) ^ ((p&7)<<4);
      bf_[j] = *(const short8*)((char*)Ps + off);
    }
    for(int i=0;i<4;i++)
      for(int j=0;j<4;j++)
        acc[i][j] = __builtin_amdgcn_mfma_f32_16x16x32_bf16(af[i], bf_[j], acc[i][j], 0,0,0);
  }
  float Dh = Dp[h];
  for(int i=0;i<4;i++){
    int lbase = 64*w + i*16 + fq*4;
    for(int r=0;r<4;r++){
      int l = lbase + r;
      float e = cse[l];
      size_t rowoff = (size_t)(row0+l)*CONV_DIM + h*64;
      size_t yb = (size_t)(row0+l)*2048 + h*64;
      for(int j=0;j<4;j++){
        int p = j*16 + fr;
        float xs = xbc[rowoff + p];
        ybuf[yb+p] += e*acc[i][j][r] + xs*Dh;
      }
    }
  }
}

// ---------------- y = rmsnorm(y * silu(z)) -> bf16 (D=2048) ----------------
__global__ __launch_bounds__(256) void k_gate_norm(const float* __restrict__ y, const float* __restrict__ zxb,
    const float* __restrict__ w, ushort* __restrict__ yb16){
  int r = blockIdx.x;
  const float* zr = zxb + (size_t)r*D_IN_PROJ;
  const float* yr = y + (size_t)r*2048;
  float v[8]; float ss=0.f;
  for(int i=0;i<8;i++){ int c=threadIdx.x+i*256; float z=zr[c]; float g=yr[c]*(z*sigmoidf_(z)); v[i]=g; ss+=g*g; }
  __shared__ float red[4];
  for(int off=32;off;off>>=1) ss += __shfl_down(ss,off,64);
  int wid=threadIdx.x>>6, lane=threadIdx.x&63;
  if(lane==0) red[wid]=ss;
  __syncthreads();
  float tot=red[0]+red[1]+red[2]+red[3];
  float rs=rsqrtf(tot*(1.f/2048.f)+1e-5f);
  for(int i=0;i<8;i++){ int c=threadIdx.x+i*256; yb16[(size_t)r*2048+c]=f2bf(v[i]*rs*w[c]); }
}

// ---------------- scorer stage 2: sigmoid(relu(h1) @ w2); h1 rows stride 384 ----------------
__global__ void k_scorer2(const float* __restrict__ h1, const float* __restrict__ w2, float* __restrict__ scores){
  int r = blockIdx.x; int lane = threadIdx.x; // 64 threads
  float s=0.f;
  for(int k=0;k<4;k++){ int c=lane+k*64; s += fmaxf(h1[(size_t)r*384+c],0.f)*w2[c]; }
  for(int off=32;off;off>>=1) s += __shfl_down(s,off,64);
  if(lane==0) scores[r]=sigmoidf_(s);
}

// ---------------- pool: parallel top-50 via float-bit bisection; exact-seq fallback on boundary tie ----------------
__global__ void k_pool(const float* __restrict__ scores,
                       int* __restrict__ countws, int* __restrict__ winners, float* __restrict__ condf){
  __shared__ float scs[BT];
  int lane = threadIdx.x;  // 64 threads
  float own[32];
  float ssum = 0.f; int vcnt = 0;
  #pragma unroll
  for(int i=0;i<32;i++){
    float s0 = scores[i*64 + lane];
    own[i] = s0; scs[i*64+lane] = s0;
    ssum += s0; vcnt += (s0 > 0.5f) ? 1 : 0;
  }
  float ts = ssum; int tv = vcnt;
  for(int off=32;off;off>>=1){ ts += __shfl_xor(ts,off,64); tv += __shfl_xor(tv,off,64); }
  int count = tv < POOL_N ? tv : POOL_N;
  bool fallback = false;
  if(tv <= POOL_N){
    int base = 0;
    #pragma unroll
    for(int i=0;i<32;i++){
      bool sel = own[i] > 0.5f;
      unsigned long long mask = __ballot(sel);
      int pre = __popcll(mask & ((1ull<<lane)-1ull));
      if(sel) winners[base + pre] = i*64 + lane;
      base += __popcll(mask);
    }
    for(int r=base+lane; r<POOL_N; r+=64) winners[r] = -1;
  } else {
    unsigned lo = 0u, hi = 0x3F800000u;
    while(hi - lo > 1u){
      unsigned mid = (lo + hi) >> 1;
      float midf = __uint_as_float(mid);
      int cnt = 0;
      #pragma unroll
      for(int i=0;i<32;i++) cnt += (own[i] >= midf) ? 1 : 0;
      for(int off=32;off;off>>=1) cnt += __shfl_xor(cnt,off,64);
      if(cnt >= POOL_N) lo = mid; else hi = mid;
    }
    float v50 = __uint_as_float(lo);
    int cl = 0;
    #pragma unroll
    for(int i=0;i<32;i++) cl += (own[i] >= v50) ? 1 : 0;
    for(int off=32;off;off>>=1) cl += __shfl_xor(cl,off,64);
    if(cl == POOL_N){
      int base = 0;
      #pragma unroll
      for(int i=0;i<32;i++){
        bool sel = own[i] >= v50;
        unsigned long long mask = __ballot(sel);
        int pre = __popcll(mask & ((1ull<<lane)-1ull));
        if(sel) winners[base + pre] = i*64 + lane;
        base += __popcll(mask);
      }
    } else fallback = true;
  }
  if(fallback){
    float prio = 0.f; int winner = -1; int cnt2 = 0;
    float curmin = 0.f; int curargmin = 0;
    for(int b0=0;b0<BT;b0+=64){
      float ow = scs[b0+lane];
      unsigned long long mask = (cnt2 < POOL_N) ? __ballot(ow > 0.5f) : __ballot(ow > curmin);
      while(mask){
        int j = __ffsll(mask) - 1;
        mask &= mask - 1ull;
        float sc = __shfl(ow, j, 64);
        if(cnt2 < POOL_N){
          if(lane == cnt2){ prio = sc; winner = b0+j; }
          cnt2++;
          if(cnt2 == POOL_N){
            float v = (lane < POOL_N)? prio : INFINITY; int idx = lane;
            for(int off=32;off;off>>=1){
              float ov = __shfl_xor(v,off,64); int oi = __shfl_xor(idx,off,64);
              if(ov < v || (ov==v && oi<idx)){ v=ov; idx=oi; }
            }
            curmin = v; curargmin = idx;
          }
        } else if(sc > curmin){
          if(lane == curargmin){ prio = sc; winner = b0+j; }
          float v = (lane < POOL_N)? prio : INFINITY; int idx = lane;
          for(int off=32;off;off>>=1){
            float ov = __shfl_xor(v,off,64); int oi = __shfl_xor(idx,off,64);
            if(ov < v || (ov==v && oi<idx)){ v=ov; idx=oi; }
          }
          curmin = v; curargmin = idx;
        }
      }
    }
    if(lane < POOL_N) winners[lane] = winner;
  }
  if(lane==0){
    countws[0] = count;
    float mean = ts*(1.f/2048.f);
    condf[0] = (mean>0.3f && count>0)? 1.f : 0.f;
  }
}

// ---------------- gather pool rows from hsq (stride 384, cols 256..319) ----------------
__global__ void k_poolg(const float* __restrict__ hsq, const int* __restrict__ winners, float* __restrict__ poolb){
  int p = blockIdx.x; int lane = threadIdx.x;
  int wi = winners[p];
  poolb[p*64+lane] = (wi>=0)? hsq[(size_t)wi*384 + 256 + lane] : 0.f;
}

// ---------------- kkT[j*64+p] = (pool @ k_w)[p][j] ----------------
__global__ void k_kk(const float* __restrict__ pool, const float* __restrict__ k_w, float* __restrict__ kkT){
  int o = blockIdx.x*256+threadIdx.x;
  if(o >= 64*POOL_N) return;
  int j = o/POOL_N, p = o%POOL_N;
  float s=0.f;
  for(int k=0;k<64;k++) s += pool[p*64+k]*k_w[k*64+j];
  kkT[j*64+p]=s;
}

// ---------------- vvT[d][p] bf16 = (pool @ v_w)[p][d]; cols p>=POOL_N zeroed ----------------
__global__ void k_vvT(const float* __restrict__ pool, const float* __restrict__ v_w, ushort* __restrict__ vvT){
  int o = blockIdx.x*256+threadIdx.x;  // 1024*64
  if(o >= 1024*64) return;
  int d = o>>6, p = o&63;
  float s=0.f;
  if(p < POOL_N)
    for(int k=0;k<64;k++) s += pool[p*64+k]*v_w[(size_t)k*1024+d];
  vvT[o] = f2bf(s);
}

// ---------------- probs: softmax(q·kkT/4, masked) -> Pb bf16 [2048][64]; q from hsq cols 320..383 ----------------
__global__ __launch_bounds__(256) void k_probs(const float* __restrict__ hsq, const float* __restrict__ kkT,
    const int* __restrict__ counti, ushort* __restrict__ Pb){
  __shared__ float qs[4][64];
  int tid = threadIdx.x;
  int w = tid>>6, lane = tid&63;
  int r = blockIdx.x*4 + w;
  qs[w][lane] = hsq[(size_t)r*384 + 320 + lane];
  __syncthreads();
  int count = counti[0];
  float logit = -1e9f;
  if(lane < POOL_N && lane < count){
    float s=0.f;
    for(int k=0;k<64;k++) s += qs[w][k]*kkT[k*64+lane];
    logit = s*0.25f;
  }
  float m = logit;
  for(int off=32;off;off>>=1) m = fmaxf(m, __shfl_xor(m,off,64));
  float e = expf(logit-m);
  float sum = e;
  for(int off=32;off;off>>=1) sum += __shfl_xor(sum,off,64);
  Pb[(size_t)r*64 + lane] = f2bf(e/sum);
}

// ---------------- PV: retr = Pb @ vvT^T (f32 + bf16 copies) ----------------
__global__ __launch_bounds__(256) void k_pv(const ushort* __restrict__ Pb, const ushort* __restrict__ vvT,
    float* __restrict__ retr, ushort* __restrict__ retrb){
  __shared__ __align__(16) ushort As[128*64];
  __shared__ __align__(16) ushort Bs[128*64];
  int m0 = (blockIdx.x >> 3)*128, n0 = (blockIdx.x & 7)*128;
  int tid = threadIdx.x;
  int row = tid>>1, half = tid&1;
  {
    const uint4* sa = (const uint4*)(Pb  + (size_t)(m0+row)*64 + half*32);
    const uint4* sb = (const uint4*)(vvT + (size_t)(n0+row)*64 + half*32);
    for(int ch=0;ch<4;ch++){
      int boff = (row<<7) + (half<<6) + (ch<<4);
      int so = boff ^ ((row&7)<<4);
      *(uint4*)((char*)As + so) = sa[ch];
      *(uint4*)((char*)Bs + so) = sb[ch];
    }
  }
  __syncthreads();
  int w=tid>>6, lane=tid&63, fr=lane&15, fq=lane>>4;
  int wr=(w>>1)*64, wc=(w&1)*64;
  f32x4 acc[4][4];
  for(int i=0;i<4;i++)for(int j=0;j<4;j++)acc[i][j]=(f32x4){0.f,0.f,0.f,0.f};
  for(int k0=0;k0<64;k0+=32){
    short8 af[4], bf_[4];
    for(int i=0;i<4;i++){
      int r = wr+i*16+fr;
      int boff = ((r<<7) + ((k0+fq*8)<<1)) ^ ((r&7)<<4);
      af[i] = *(const short8*)((char*)As + boff);
    }
    for(int j=0;j<4;j++){
      int r = wc+j*16+fr;
      int boff = ((r<<7) + ((k0+fq*8)<<1)) ^ ((r&7)<<4);
      bf_[j] = *(const short8*)((char*)Bs + boff);
    }
    for(int i=0;i<4;i++)
      for(int j=0;j<4;j++)
        acc[i][j] = __builtin_amdgcn_mfma_f32_16x16x32_bf16(af[i], bf_[j], acc[i][j], 0,0,0);
  }
  int rbase = m0 + wr + fq*4;
  for(int i=0;i<4;i++){
    for(int j=0;j<4;j++){
      int col = n0 + wc + j*16 + fr;
      for(int r=0;r<4;r++){
        float v = acc[i][j][r];
        size_t idx = (size_t)(rbase + i*16 + r)*1024 + col;
        retr[idx] = v;
        retrb[idx] = f2bf(v);
      }
    }
  }
}

static inline void gemmb(hipStream_t s, const ushort*A,const ushort*Bt,float*C,ushort*Cb,int M,int N,int K,int act){
  int nbx = (N+127)/128;
  int nwg = nbx * (M/128);
  hipLaunchKernelGGL(gemm_bf16,dim3(nwg),dim3(256),0,s,A,Bt,C,Cb,M,N,K,act,nbx);
}
static inline void gemmb64(hipStream_t s, const ushort*A,const ushort*Bt,float*C,ushort*Cb,int M,int N,int K,int act){
  int nbx = (N+127)/128;
  int nwg = nbx * (M/64);
  hipLaunchKernelGGL(gemm_bf16_64,dim3(nwg),dim3(256),0,s,A,Bt,C,Cb,M,N,K,act,nbx);
}

extern "C" void kernel_launch(void* const* d_in, const int* in_sizes, int n_in,
                              void* d_out, int out_size, void* d_ws, size_t ws_size,
                              hipStream_t stream) {
  const float* x        = (const float*)d_in[0];
  const float* norm_w   = (const float*)d_in[1];
  const float* in_proj_w= (const float*)d_in[2];
  const float* conv_w   = (const float*)d_in[3];
  const float* conv_b   = (const float*)d_in[4];
  const float* dt_bias  = (const float*)d_in[5];
  const float* A_log    = (const float*)d_in[6];
  const float* Dp       = (const float*)d_in[7];
  const float* ssm_norm_w=(const float*)d_in[8];
  const float* out_proj_w=(const float*)d_in[9];
  const float* scorer_w1= (const float*)d_in[10];
  const float* scorer_w2= (const float*)d_in[11];
  const float* summ_w   = (const float*)d_in[12];
  const float* q_w      = (const float*)d_in[13];
  const float* k_w      = (const float*)d_in[14];
  const float* v_w      = (const float*)d_in[15];
  const float* gate_w   = (const float*)d_in[16];
  float* out = (float*)d_out;

  unsigned char* base = (unsigned char*)d_ws;
  size_t off = 0;
  auto FB = [&](size_t bytes)->void*{ void* p = base+off; off = (off+bytes+255)&~(size_t)255; return p; };
  float* zxb   = (float*)FB((size_t)2048*D_IN_PROJ*4);
  float* dtb   = (float*)FB((size_t)2048*32*4);
  float* xbc   = (float*)FB((size_t)2048*CONV_DIM*4);
  float* csb   = (float*)FB((size_t)256*256*4);
  float* sdA   = (float*)FB(1024);
  float* states= (float*)FB((size_t)256*8192*4);
  float* prevb = (float*)FB((size_t)256*8192*4);
  float* ybuf  = (float*)FB((size_t)2048*2048*4);
  float* yout  = (float*)FB((size_t)2048*1024*4);
  float* scores= (float*)FB(2048*4);
  float* summ  = (float*)FB((size_t)2048*64*4);
  float* qb    = (float*)FB((size_t)2048*64*4);
  float* poolb = (float*)FB(POOL_N*64*4);
  float* prios = (float*)FB(256);
  float* miscf = (float*)FB(256);
  int*   counti= (int*)FB(256);
  int*   winners=(int*)FB(256);
  unsigned char* RX = (unsigned char*)FB((size_t)4194304);
  unsigned char* W1 = (unsigned char*)FB((size_t)8978432);

  ushort* xnb   = (ushort*)RX;
  ushort* scsqT = (ushort*)RX;                  // [384][1024] bf16
  float*  hsq   = (float*) (RX + 786432);       // [2048][384] f32
  float*  kkT   = (float*) ((unsigned char*)qb + 262144);
  ushort* vvT   = (ushort*)summ;
  ushort* Pb    = (ushort*)qb;
  ushort* inT   = (ushort*)W1;
  ushort* outT  = (ushort*)W1;
  ushort* gateT = (ushort*)(W1 + 4194304);
  float*  Gt    = yout;
  ushort* ybf   = (ushort*)prevb;
  float*  retr  = states;
  ushort* retrb = (ushort*)ybuf;
  ushort* youtb = (ushort*)((unsigned char*)ybuf + 8388608);
  (void)prios;

  hipLaunchKernelGGL(k_transpose_cvt, dim3(137,32), dim3(256), 0, stream, in_proj_w, inT, 1024, 4384);
  k_rmsnorm_x<<<2048,256,0,stream>>>(x, norm_w, xnb);
  gemmb(stream, xnb, inT, zxb, nullptr, 2048, D_IN_PROJ, 1024, 0);
  hipLaunchKernelGGL(k_transpose_cvt, dim3(32,64), dim3(256), 0, stream, out_proj_w, outT, 2048, 1024);
  hipLaunchKernelGGL(k_transpose_cvt, dim3(32,64), dim3(256), 0, stream, gate_w, gateT, 2048, 1024);
  hipLaunchKernelGGL(k_transpose_cvt, dim3(8,32), dim3(256), 0, stream, scorer_w1, scsqT, 1024, 256);
  hipLaunchKernelGGL(k_transpose_cvt, dim3(2,32), dim3(256), 0, stream, summ_w, scsqT + 256*1024, 1024, 64);
  hipLaunchKernelGGL(k_transpose_cvt, dim3(2,32), dim3(256), 0, stream, q_w, scsqT + 320*1024, 1024, 64);
  k_dt<<<256,256,0,stream>>>(zxb, dt_bias, dtb);
  k_conv4<<<4608,256,0,stream>>>(zxb, conv_w, conv_b, xbc);
  k_gt<<<2048,256,0,stream>>>(xbc, Gt);
  k_ssd1w<<<256,512,0,stream>>>(xbc, dtb, A_log, Gt, ybuf, states, csb, sdA);
  k_ssd2<<<2048,256,0,stream>>>(states, sdA, prevb);
  k_ssd3m<<<256,256,0,stream>>>(xbc, csb, prevb, Dp, ybuf);
  k_gate_norm<<<2048,256,0,stream>>>(ybuf, zxb, ssm_norm_w, ybf);
  gemmb64(stream, ybf, outT, yout, youtb, 2048, 1024, 2048, 0);
  gemmb64(stream, youtb, scsqT, hsq, nullptr, 2048, 384, 1024, 0);
  k_scorer2<<<2048,64,0,stream>>>(hsq, scorer_w2, scores);
  k_pool<<<1,64,0,stream>>>(scores, counti, winners, miscf);
  k_poolg<<<POOL_N,64,0,stream>>>(hsq, winners, poolb);
  k_kk<<<(64*POOL_N+255)/256,256,0,stream>>>(poolb, k_w, kkT);
  k_vvT<<<256,256,0,stream>>>(poolb, v_w, vvT);
  k_probs<<<512,256,0,stream>>>(hsq, kkT, counti, Pb);
  k_pv<<<128,256,0,stream>>>(Pb, vvT, retr, retrb);
  hipLaunchKernelGGL(gemm_gate64, dim3(256), dim3(256), 0, stream,
                     youtb, retrb, gateT, x, yout, retr, miscf, out);
  (void)in_sizes; (void)n_in; (void)out_size; (void)ws_size;
}

// Round 18
// 272.314 us; speedup vs baseline: 1.0405x; 1.0405x over previous
//
#include <hip/hip_runtime.h>
#include <math.h>

#define NHEADS 32
#define D_INNER 2048
#define CONV_DIM 2304
#define D_IN_PROJ 4384
#define POOL_N 50
#define BT 2048

typedef __attribute__((ext_vector_type(8))) short short8;
typedef __attribute__((ext_vector_type(4))) float f32x4;

__device__ __forceinline__ float sigmoidf_(float x){ return 1.f/(1.f+expf(-x)); }
__device__ __forceinline__ ushort f2bf(float f){
  union{float f; unsigned u;} v; v.f=f;
  unsigned r = v.u + 0x7fffu + ((v.u>>16)&1u);
  return (ushort)(r>>16);
}
__device__ __forceinline__ void gload16(const void* g, void* l){
  __builtin_amdgcn_global_load_lds(
    (const __attribute__((address_space(1))) unsigned int*)g,
    (__attribute__((address_space(3))) unsigned int*)l, 16, 0, 0);
}

// ---------------- RMSNorm on x (D=1024) -> bf16 ----------------
__global__ __launch_bounds__(256) void k_rmsnorm_x(const float* __restrict__ x, const float* __restrict__ w, ushort* __restrict__ xn){
  int r = blockIdx.x;
  const float* xr = x + (size_t)r*1024;
  float v[4]; float ss=0.f;
  for(int i=0;i<4;i++){ v[i]=xr[threadIdx.x+i*256]; ss+=v[i]*v[i]; }
  __shared__ float red[4];
  for(int off=32;off;off>>=1) ss += __shfl_down(ss,off,64);
  int wid=threadIdx.x>>6, lane=threadIdx.x&63;
  if(lane==0) red[wid]=ss;
  __syncthreads();
  float tot=red[0]+red[1]+red[2]+red[3];
  float rs=rsqrtf(tot*(1.f/1024.f)+1e-5f);
  for(int i=0;i<4;i++){ int c=threadIdx.x+i*256; xn[(size_t)r*1024+c]=f2bf(v[i]*rs*w[c]); }
}

// ---------------- transpose + cvt: src f32 [R][C] -> dst bf16 [C][R] ----------------
__global__ __launch_bounds__(256) void k_transpose_cvt(const float* __restrict__ src, ushort* __restrict__ dst, int R, int C){
  __shared__ float tile[32][33];
  int c0 = blockIdx.x*32, r0 = blockIdx.y*32;
  int tx = threadIdx.x&31, ty = threadIdx.x>>5;
  for(int i=0;i<4;i++){ int r = r0+ty+i*8; tile[ty+i*8][tx] = src[(size_t)r*C + c0+tx]; }
  __syncthreads();
  for(int i=0;i<4;i++){ int c = c0+ty+i*8; dst[(size_t)c*R + r0+tx] = f2bf(tile[tx][ty+i*8]); }
}

// ---------------- bf16 MFMA GEMM (BM=128): BK=64, dbuf LDS, counted vmcnt, XOR-swizzled ----------------
__global__ __launch_bounds__(256) void gemm_bf16(const ushort* __restrict__ A, const ushort* __restrict__ Bt,
    float* __restrict__ C, ushort* __restrict__ Cb, int M, int N, int K, int act, int nbx){
  __shared__ __align__(16) ushort As[2][128*64];
  __shared__ __align__(16) ushort Bs[2][128*64];
  int wg = blockIdx.x, nwg = gridDim.x;
  if((nwg & 7)==0){ int cpx = nwg>>3; wg = (wg&7)*cpx + (wg>>3); }
  int bx = wg % nbx, by = wg / nbx;
  int n0 = bx*128, m0 = by*128;
  int tid = threadIdx.x;
  int lane = tid&63, w = tid>>6;
  int wr = (w>>1)*64, wc = (w&1)*64;
  f32x4 acc[4][4];
  for(int i=0;i<4;i++)for(int j=0;j<4;j++)acc[i][j]=(f32x4){0.f,0.f,0.f,0.f};
  int col16s = (tid&7) ^ ((tid>>3)&7);
  int r0t = tid>>3;
  const char* AG[4]; const char* BG[4];
  #pragma unroll
  for(int c=0;c<4;c++){
    int r = r0t + c*32;
    AG[c] = (const char*)(A + (size_t)(m0+r)*K + col16s*8);
    int br = n0 + r;
    BG[c] = (const char*)(Bt + (size_t)((br<N)?br:0)*K + col16s*8);
  }
  int nk = K >> 6;
  int fr = lane&15, fq = lane>>4;
  {
    #pragma unroll
    for(int c=0;c<4;c++){
      gload16(AG[c], (char*)As[0] + (c*256 + w*64)*16);
      gload16(BG[c], (char*)Bs[0] + (c*256 + w*64)*16);
    }
  }
  for(int ks=0; ks<nk; ks++){
    int cur = ks&1;
    if(ks+1 < nk){
      size_t kb = (size_t)(ks+1)*128;
      #pragma unroll
      for(int c=0;c<4;c++){
        gload16(AG[c]+kb, (char*)As[cur^1] + (c*256 + w*64)*16);
        gload16(BG[c]+kb, (char*)Bs[cur^1] + (c*256 + w*64)*16);
      }
      asm volatile("s_waitcnt vmcnt(8)" ::: "memory");
    } else {
      asm volatile("s_waitcnt vmcnt(0)" ::: "memory");
    }
    __builtin_amdgcn_s_barrier();
    __builtin_amdgcn_sched_barrier(0);
    #pragma unroll
    for(int kk=0;kk<2;kk++){
      short8 af[4], bfr[4];
      #pragma unroll
      for(int i=0;i<4;i++){
        int rl = wr+i*16+fr;
        int off = ((rl<<7) + (kk<<6) + (fq<<4)) ^ ((rl&7)<<4);
        af[i] = *(const short8*)((char*)As[cur] + off);
      }
      #pragma unroll
      for(int j=0;j<4;j++){
        int rl = wc+j*16+fr;
        int off = ((rl<<7) + (kk<<6) + (fq<<4)) ^ ((rl&7)<<4);
        bfr[j] = *(const short8*)((char*)Bs[cur] + off);
      }
      #pragma unroll
      for(int i=0;i<4;i++)
        #pragma unroll
        for(int j=0;j<4;j++)
          acc[i][j] = __builtin_amdgcn_mfma_f32_16x16x32_bf16(af[i], bfr[j], acc[i][j], 0,0,0);
    }
    asm volatile("s_waitcnt lgkmcnt(0)" ::: "memory");
    __builtin_amdgcn_sched_barrier(0);
    __builtin_amdgcn_s_barrier();
  }
  int rbase = m0 + wr + fq*4;
  for(int i=0;i<4;i++){
    for(int j=0;j<4;j++){
      int col = n0 + wc + j*16 + fr;
      if(col < N){
        for(int r=0;r<4;r++){
          float v = acc[i][j][r];
          if(act) v = fmaxf(v,0.f);
          size_t idx = (size_t)(rbase + i*16 + r)*N + col;
          C[idx] = v;
          if(Cb) Cb[idx] = f2bf(v);
        }
      }
    }
  }
}

// ---------------- bf16 MFMA GEMM (BM=64): for M=2048,N<=1024 shapes (grid doubling) ----------------
__global__ __launch_bounds__(256) void gemm_bf16_64(const ushort* __restrict__ A, const ushort* __restrict__ Bt,
    float* __restrict__ C, ushort* __restrict__ Cb, int M, int N, int K, int act, int nbx){
  __shared__ __align__(16) ushort As[2][64*64];
  __shared__ __align__(16) ushort Bs[2][128*64];
  int wg = blockIdx.x, nwg = gridDim.x;
  if((nwg & 7)==0){ int cpx = nwg>>3; wg = (wg&7)*cpx + (wg>>3); }
  int bx = wg % nbx, by = wg / nbx;
  int n0 = bx*128, m0 = by*64;
  int tid = threadIdx.x;
  int lane = tid&63, w = tid>>6;
  f32x4 acc[4][2];
  for(int i=0;i<4;i++)for(int j=0;j<2;j++)acc[i][j]=(f32x4){0.f,0.f,0.f,0.f};
  int col16s = (tid&7) ^ ((tid>>3)&7);
  int r0t = tid>>3;
  const char* AG[2]; const char* BG[4];
  #pragma unroll
  for(int c=0;c<2;c++){
    int r = r0t + c*32;
    AG[c] = (const char*)(A + (size_t)(m0+r)*K + col16s*8);
  }
  #pragma unroll
  for(int c=0;c<4;c++){
    int br = n0 + r0t + c*32;
    BG[c] = (const char*)(Bt + (size_t)((br<N)?br:0)*K + col16s*8);
  }
  int nk = K >> 6;
  int fr = lane&15, fq = lane>>4;
  {
    #pragma unroll
    for(int c=0;c<2;c++) gload16(AG[c], (char*)As[0] + (c*256 + w*64)*16);
    #pragma unroll
    for(int c=0;c<4;c++) gload16(BG[c], (char*)Bs[0] + (c*256 + w*64)*16);
  }
  for(int ks=0; ks<nk; ks++){
    int cur = ks&1;
    if(ks+1 < nk){
      size_t kb = (size_t)(ks+1)*128;
      #pragma unroll
      for(int c=0;c<2;c++) gload16(AG[c]+kb, (char*)As[cur^1] + (c*256 + w*64)*16);
      #pragma unroll
      for(int c=0;c<4;c++) gload16(BG[c]+kb, (char*)Bs[cur^1] + (c*256 + w*64)*16);
      asm volatile("s_waitcnt vmcnt(6)" ::: "memory");
    } else {
      asm volatile("s_waitcnt vmcnt(0)" ::: "memory");
    }
    __builtin_amdgcn_s_barrier();
    __builtin_amdgcn_sched_barrier(0);
    #pragma unroll
    for(int kk=0;kk<2;kk++){
      short8 af[4], bfr[2];
      #pragma unroll
      for(int i=0;i<4;i++){
        int rl = i*16+fr;
        int off = ((rl<<7) + (kk<<6) + (fq<<4)) ^ ((rl&7)<<4);
        af[i] = *(const short8*)((char*)As[cur] + off);
      }
      #pragma unroll
      for(int j=0;j<2;j++){
        int rl = w*32+j*16+fr;
        int off = ((rl<<7) + (kk<<6) + (fq<<4)) ^ ((rl&7)<<4);
        bfr[j] = *(const short8*)((char*)Bs[cur] + off);
      }
      #pragma unroll
      for(int i=0;i<4;i++)
        #pragma unroll
        for(int j=0;j<2;j++)
          acc[i][j] = __builtin_amdgcn_mfma_f32_16x16x32_bf16(af[i], bfr[j], acc[i][j], 0,0,0);
    }
    asm volatile("s_waitcnt lgkmcnt(0)" ::: "memory");
    __builtin_amdgcn_sched_barrier(0);
    __builtin_amdgcn_s_barrier();
  }
  int rbase = m0 + fq*4;
  for(int i=0;i<4;i++){
    for(int j=0;j<2;j++){
      int col = n0 + w*32 + j*16 + fr;
      if(col < N){
        for(int r=0;r<4;r++){
          float v = acc[i][j][r];
          if(act) v = fmaxf(v,0.f);
          size_t idx = (size_t)(rbase + i*16 + r)*N + col;
          C[idx] = v;
          if(Cb) Cb[idx] = f2bf(v);
        }
      }
    }
  }
}

// ---------------- gate GEMM (BM=64): A=[youtb|retrb] split at k=1024, fused final epilogue ----------------
__global__ __launch_bounds__(256) void gemm_gate64(const ushort* __restrict__ Ay, const ushort* __restrict__ Ar,
    const ushort* __restrict__ Bt, const float* __restrict__ x, const float* __restrict__ yout,
    const float* __restrict__ retr, const float* __restrict__ condf, float* __restrict__ out){
  __shared__ __align__(16) ushort As[2][64*64];
  __shared__ __align__(16) ushort Bs[2][128*64];
  const int nbx = 8;
  int wg = blockIdx.x, nwg = gridDim.x;
  if((nwg & 7)==0){ int cpx = nwg>>3; wg = (wg&7)*cpx + (wg>>3); }
  int bx = wg % nbx, by = wg / nbx;
  int n0 = bx*128, m0 = by*64;
  int tid = threadIdx.x;
  int lane = tid&63, w = tid>>6;
  f32x4 acc[4][2];
  for(int i=0;i<4;i++)for(int j=0;j<2;j++)acc[i][j]=(f32x4){0.f,0.f,0.f,0.f};
  int col16s = (tid&7) ^ ((tid>>3)&7);
  int r0t = tid>>3;
  const char* AGy[2]; const char* AGr[2]; const char* BG[4];
  #pragma unroll
  for(int c=0;c<2;c++){
    int r = r0t + c*32;
    AGy[c] = (const char*)(Ay + (size_t)(m0+r)*1024 + col16s*8);
    AGr[c] = (const char*)(Ar + (size_t)(m0+r)*1024 + col16s*8);
  }
  #pragma unroll
  for(int c=0;c<4;c++){
    int br = n0 + r0t + c*32;
    BG[c] = (const char*)(Bt + (size_t)br*2048 + col16s*8);
  }
  const int nk = 32;
  int fr = lane&15, fq = lane>>4;
  {
    #pragma unroll
    for(int c=0;c<2;c++) gload16(AGy[c], (char*)As[0] + (c*256 + w*64)*16);
    #pragma unroll
    for(int c=0;c<4;c++) gload16(BG[c],  (char*)Bs[0] + (c*256 + w*64)*16);
  }
  for(int ks=0; ks<nk; ks++){
    int cur = ks&1;
    if(ks+1 < nk){
      int t = ks+1;
      size_t kbA = (size_t)((t<16)? t : t-16)*128;
      size_t kbB = (size_t)t*128;
      #pragma unroll
      for(int c=0;c<2;c++){
        const char* asrc = (t<16) ? (AGy[c]+kbA) : (AGr[c]+kbA);
        gload16(asrc, (char*)As[cur^1] + (c*256 + w*64)*16);
      }
      #pragma unroll
      for(int c=0;c<4;c++) gload16(BG[c]+kbB, (char*)Bs[cur^1] + (c*256 + w*64)*16);
      asm volatile("s_waitcnt vmcnt(6)" ::: "memory");
    } else {
      asm volatile("s_waitcnt vmcnt(0)" ::: "memory");
    }
    __builtin_amdgcn_s_barrier();
    __builtin_amdgcn_sched_barrier(0);
    #pragma unroll
    for(int kk=0;kk<2;kk++){
      short8 af[4], bfr[2];
      #pragma unroll
      for(int i=0;i<4;i++){
        int rl = i*16+fr;
        int off = ((rl<<7) + (kk<<6) + (fq<<4)) ^ ((rl&7)<<4);
        af[i] = *(const short8*)((char*)As[cur] + off);
      }
      #pragma unroll
      for(int j=0;j<2;j++){
        int rl = w*32+j*16+fr;
        int off = ((rl<<7) + (kk<<6) + (fq<<4)) ^ ((rl&7)<<4);
        bfr[j] = *(const short8*)((char*)Bs[cur] + off);
      }
      #pragma unroll
      for(int i=0;i<4;i++)
        #pragma unroll
        for(int j=0;j<2;j++)
          acc[i][j] = __builtin_amdgcn_mfma_f32_16x16x32_bf16(af[i], bfr[j], acc[i][j], 0,0,0);
    }
    asm volatile("s_waitcnt lgkmcnt(0)" ::: "memory");
    __builtin_amdgcn_sched_barrier(0);
    __builtin_amdgcn_s_barrier();
  }
  float cond = condf[0];
  int rbase = m0 + fq*4;
  for(int i=0;i<4;i++){
    for(int j=0;j<2;j++){
      int col = n0 + w*32 + j*16 + fr;
      for(int r=0;r<4;r++){
        size_t idx = (size_t)(rbase + i*16 + r)*1024 + col;
        float gv = sigmoidf_(acc[i][j][r]);
        out[idx] = x[idx] + yout[idx] + cond*gv*retr[idx];
      }
    }
  }
}

// ---------------- causal depthwise conv (k=4) + silu, 4 channels/thread; tail blocks do dt softplus ----------------
__global__ void k_conv4(const float* __restrict__ zxb, const float* __restrict__ cw, const float* __restrict__ cb,
                        float* __restrict__ xbc, const float* __restrict__ dt_bias, float* __restrict__ dtb){
  int o = blockIdx.x*256+threadIdx.x;
  if(o >= 2048*576){
    int o2 = o - 2048*576;    // 0 .. 65535: dt = softplus(zxb[:, -32:] + bias)
    int r = o2>>5, h = o2&31;
    float v = zxb[(size_t)r*D_IN_PROJ + 4352 + h] + dt_bias[h];
    dtb[o2] = (v>20.f) ? v : log1pf(expf(v));
    return;
  }
  int ch4 = (o % 576)*4; int rt = o / 576;
  int b = rt>>10, t = rt&1023;
  float a[4];
  { float4 cbv = *(const float4*)(cb + ch4); a[0]=cbv.x; a[1]=cbv.y; a[2]=cbv.z; a[3]=cbv.w; }
  float cwa[4][4];
  for(int c2=0;c2<4;c2++){
    float4 v = *(const float4*)(cw + (ch4+c2)*4);
    cwa[c2][0]=v.x; cwa[c2][1]=v.y; cwa[c2][2]=v.z; cwa[c2][3]=v.w;
  }
  for(int k=0;k<4;k++){
    int tt = t-3+k;
    if(tt>=0){
      float4 v = *(const float4*)(zxb + (size_t)(b*1024+tt)*D_IN_PROJ + 2048 + ch4);
      a[0] += v.x*cwa[0][k]; a[1] += v.y*cwa[1][k];
      a[2] += v.z*cwa[2][k]; a[3] += v.w*cwa[3][k];
    }
  }
  float4 o4;
  o4.x = a[0]*sigmoidf_(a[0]); o4.y = a[1]*sigmoidf_(a[1]);
  o4.z = a[2]*sigmoidf_(a[2]); o4.w = a[3]*sigmoidf_(a[3]);
  *(float4*)(xbc + (size_t)rt*CONV_DIM + ch4) = o4;
}

// ---------------- G^T per (b,c): Gt[s*256+l] = dot(C[l], B[s]) ----------------
__global__ __launch_bounds__(256) void k_gt(const float* __restrict__ xbc, float* __restrict__ Gt){
  int bc = blockIdx.x >> 8;
  int tile = blockIdx.x & 255;
  int l0 = (tile>>4)<<4, s0 = (tile&15)<<4;
  int b = bc>>2, c = bc&3;
  int row0 = b*1024 + c*256;
  __shared__ float Cs[16][130], Bs2[16][130];
  int tid = threadIdx.x;
  for(int i=0;i<8;i++){ int e=tid+i*256; int rr=e>>7, n=e&127;
    Cs[rr][n]  = xbc[(size_t)(row0+l0+rr)*CONV_DIM + 2176 + n];
    Bs2[rr][n] = xbc[(size_t)(row0+s0+rr)*CONV_DIM + 2048 + n];
  }
  __syncthreads();
  int tx = tid&15, ty = tid>>4;
  float acc=0.f;
  for(int n=0;n<128;n++) acc += Cs[tx][n]*Bs2[ty][n];
  Gt[(size_t)bc*65536 + (size_t)(s0+ty)*256 + (l0+tx)] = acc;
}

// ---------------- SSD per (b,c,h): 512 threads, wave-specialized ----------------
__global__ __launch_bounds__(512) void k_ssd1w(const float* __restrict__ xbc, const float* __restrict__ dtb,
    const float* __restrict__ A_log, const float* __restrict__ Gt,
    float* __restrict__ ybuf, float* __restrict__ states, float* __restrict__ csb, float* __restrict__ sdA){
  int blk = blockIdx.x;      // (b*4+c)*32+h
  int bc = blk>>5, h = blk&31;
  int b = bc>>2, c = bc&3;
  int row0 = b*1024 + c*256;
  int tid = threadIdx.x;
  __shared__ float cs[256];
  __shared__ float dts[256];
  __shared__ float dec[256];
  __shared__ __align__(16) ushort xdT[64*256];
  __shared__ __align__(16) ushort Mw[4*64*32];
  __shared__ __align__(16) ushort Bw[4*32*256];
  float Ah = -expf(A_log[h]);
  if(tid < 256){
    float dtv = dtb[(size_t)(row0+tid)*32 + h];
    dts[tid] = dtv;
    cs[tid] = dtv*Ah;
  }
  __syncthreads();
  for(int o=1;o<256;o<<=1){
    float add = 0.f;
    if(tid<256 && tid>=o) add = cs[tid-o];
    __syncthreads();
    if(tid<256) cs[tid] += add;
    __syncthreads();
  }
  float cslast = cs[255];
  if(tid < 256){
    float csl = cs[tid];
    csb[blk*256+tid] = csl;
    dec[tid] = expf(cslast - csl);
    if(tid==0) sdA[blk] = cslast;
  }
  {
    int p = tid&63, g = tid>>6;
    for(int i=0;i<32;i++){
      int l = g + 8*i;
      float v = xbc[(size_t)(row0+l)*CONV_DIM + h*64 + p] * dts[l];
      int off = ((p<<9) + (l<<1)) ^ ((p&7)<<4);
      *(ushort*)((char*)xdT + off) = f2bf(v);
    }
  }
  __syncthreads();

  int w = tid>>6, lane = tid&63;
  int fr = lane&15, fq = lane>>4;
  const float* gt = Gt + (size_t)bc*65536;
  if(w < 4){
    int rowl = w*64 + lane;
    float csl_w = cs[rowl];
    f32x4 accY[4][4];
    for(int i=0;i<4;i++)for(int j=0;j<4;j++)accY[i][j]=(f32x4){0.f,0.f,0.f,0.f};
    int nk = 2*(w+1);
    for(int ks=0; ks<nk; ks++){
      int s0 = ks*32;
      float cs_s0 = cs[s0];
      float ev = expf(cs_s0 - cs[s0 + (lane&31)]);
      float el = expf(csl_w - cs_s0);
      for(int j=0;j<4;j++){
        short8 mp;
        for(int k=0;k<8;k++){
          int s2 = j*8+k;
          int s = s0 + s2;
          float gv = gt[(size_t)s*256 + rowl];
          float esv = __shfl(ev, s2, 64);
          float m = (s <= rowl) ? gv*el*esv : 0.f;
          mp[k] = (short)f2bf(m);
        }
        int off = (w<<12) + ((((lane)<<6) + (j<<4)) ^ ((lane&7)<<4));
        *(short8*)((char*)Mw + off) = mp;
      }
      asm volatile("s_waitcnt lgkmcnt(0)" ::: "memory");
      __builtin_amdgcn_sched_barrier(0);
      short8 af[4], bv4[4];
      for(int i=0;i<4;i++){
        int lp = i*16 + fr;
        int off = (w<<12) + (((lp<<6) + (fq<<4)) ^ ((lp&7)<<4));
        af[i] = *(const short8*)((char*)Mw + off);
      }
      for(int j=0;j<4;j++){
        int p = j*16 + fr;
        int off = ((p<<9) + ((s0 + fq*8)<<1)) ^ ((p&7)<<4);
        bv4[j] = *(const short8*)((char*)xdT + off);
      }
      for(int i=0;i<4;i++)
        for(int j=0;j<4;j++)
          accY[i][j] = __builtin_amdgcn_mfma_f32_16x16x32_bf16(af[i], bv4[j], accY[i][j], 0,0,0);
      asm volatile("" ::: "memory");
    }
    for(int i=0;i<4;i++){
      int l = 64*w + i*16 + fq*4;
      for(int j=0;j<4;j++){
        int p = j*16 + fr;
        for(int r=0;r<4;r++)
          ybuf[(size_t)(row0+l+r)*2048 + h*64 + p] = accY[i][j][r];
      }
    }
  } else {
    int sw = w-4, nbase = sw*32;
    {
      int nn = lane&31, half = lane>>5;
      for(int i=0;i<128;i++){
        int l = half + 2*i;
        float v = xbc[(size_t)(row0+l)*CONV_DIM + 2048 + nbase + nn] * dec[l];
        int off = (sw<<14) + (((nn<<9) + (l<<1)) ^ ((nn&7)<<4));
        *(ushort*)((char*)Bw + off) = f2bf(v);
      }
    }
    asm volatile("s_waitcnt lgkmcnt(0)" ::: "memory");
    __builtin_amdgcn_sched_barrier(0);
    f32x4 accS[4][2];
    for(int i=0;i<4;i++)for(int j=0;j<2;j++)accS[i][j]=(f32x4){0.f,0.f,0.f,0.f};
    for(int ks=0;ks<8;ks++){
      int l0 = ks*32;
      short8 aS[4], bS[2];
      for(int i=0;i<4;i++){
        int p = i*16 + fr;
        int off = ((p<<9) + ((l0+fq*8)<<1)) ^ ((p&7)<<4);
        aS[i] = *(const short8*)((char*)xdT + off);
      }
      for(int j=0;j<2;j++){
        int nn = j*16 + fr;
        int off = (sw<<14) + (((nn<<9) + ((l0+fq*8)<<1)) ^ ((nn&7)<<4));
        bS[j] = *(const short8*)((char*)Bw + off);
      }
      for(int i=0;i<4;i++)
        for(int j=0;j<2;j++)
          accS[i][j] = __builtin_amdgcn_mfma_f32_16x16x32_bf16(aS[i], bS[j], accS[i][j], 0,0,0);
    }
    for(int i=0;i<4;i++){
      int p = i*16 + fq*4;
      for(int j=0;j<2;j++){
        int n = nbase + j*16 + fr;
        for(int r=0;r<4;r++)
          states[(size_t)blk*8192 + (size_t)(p+r)*128 + n] = accS[i][j][r];
      }
    }
  }
}

// ---------------- chunk scan over c=0..3 ----------------
__global__ __launch_bounds__(256) void k_ssd2(const float* __restrict__ states, const float* __restrict__ sdA, float* __restrict__ prevb){
  int idx = blockIdx.x*256 + threadIdx.x;
  int e = idx & 8191;
  int h = (idx >> 13) & 31;
  int b = idx >> 18;
  float run = 0.f;
  for(int c=0;c<4;c++){
    int sblk = (b*4+c)*32 + h;
    size_t base = (size_t)sblk*8192 + e;
    prevb[base] = run;
    run = (run + states[base]) * expf(sdA[sblk]);
  }
}

// ---------------- y_off = C @ prev^T via MFMA; += xs*D into ybuf ----------------
__global__ __launch_bounds__(256) void k_ssd3m(const float* __restrict__ xbc, const float* __restrict__ csb,
    const float* __restrict__ prevb, const float* __restrict__ Dp, float* __restrict__ ybuf){
  int blk = blockIdx.x; int bc = blk>>5, h = blk&31; int b=bc>>2, c=bc&3;
  int row0 = b*1024+c*256;
  int tid = threadIdx.x;
  __shared__ __align__(16) ushort Cs[256*128];
  __shared__ __align__(16) ushort Ps[64*128];
  __shared__ float cse[256];
  for(int i=0;i<128;i++){
    int id = tid + i*256;
    int n = id & 127, l = id >> 7;
    float v = xbc[(size_t)(row0+l)*CONV_DIM + 2176 + n];
    int off = ((l<<8) + (n<<1)) ^ ((l&7)<<4);
    *(ushort*)((char*)Cs + off) = f2bf(v);
  }
  for(int i=0;i<32;i++){
    int id = tid + i*256;
    int n = id & 127, p = id >> 7;
    float v = prevb[(size_t)blk*8192 + id];
    int off = ((p<<8) + (n<<1)) ^ ((p&7)<<4);
    *(ushort*)((char*)Ps + off) = f2bf(v);
  }
  cse[tid] = expf(csb[blk*256+tid]);
  __syncthreads();
  int w=tid>>6, lane=tid&63, fr=lane&15, fq=lane>>4;
  f32x4 acc[4][4];
  for(int i=0;i<4;i++)for(int j=0;j<4;j++)acc[i][j]=(f32x4){0.f,0.f,0.f,0.f};
  for(int ks=0;ks<4;ks++){
    int n0 = ks*32;
    short8 af[4], bf_[4];
    for(int i=0;i<4;i++){
      int l = w*64 + i*16 + fr;
      int off = ((l<<8) + ((n0+fq*8)<<1)) ^ ((l&7)<<4);
      af[i] = *(const short8*)((char*)Cs + off);
    }
    for(int j=0;j<4;j++){
      int p = j*16 + fr;
      int off = ((p<<8) + ((n0+fq*8)<<1)) ^ ((p&7)<<4);
      bf_[j] = *(const short8*)((char*)Ps + off);
    }
    for(int i=0;i<4;i++)
      for(int j=0;j<4;j++)
        acc[i][j] = __builtin_amdgcn_mfma_f32_16x16x32_bf16(af[i], bf_[j], acc[i][j], 0,0,0);
  }
  float Dh = Dp[h];
  for(int i=0;i<4;i++){
    int lbase = 64*w + i*16 + fq*4;
    for(int r=0;r<4;r++){
      int l = lbase + r;
      float e = cse[l];
      size_t rowoff = (size_t)(row0+l)*CONV_DIM + h*64;
      size_t yb = (size_t)(row0+l)*2048 + h*64;
      for(int j=0;j<4;j++){
        int p = j*16 + fr;
        float xs = xbc[rowoff + p];
        ybuf[yb+p] += e*acc[i][j][r] + xs*Dh;
      }
    }
  }
}

// ---------------- y = rmsnorm(y * silu(z)) -> bf16 (D=2048) ----------------
__global__ __launch_bounds__(256) void k_gate_norm(const float* __restrict__ y, const float* __restrict__ zxb,
    const float* __restrict__ w, ushort* __restrict__ yb16){
  int r = blockIdx.x;
  const float* zr = zxb + (size_t)r*D_IN_PROJ;
  const float* yr = y + (size_t)r*2048;
  float v[8]; float ss=0.f;
  for(int i=0;i<8;i++){ int c=threadIdx.x+i*256; float z=zr[c]; float g=yr[c]*(z*sigmoidf_(z)); v[i]=g; ss+=g*g; }
  __shared__ float red[4];
  for(int off=32;off;off>>=1) ss += __shfl_down(ss,off,64);
  int wid=threadIdx.x>>6, lane=threadIdx.x&63;
  if(lane==0) red[wid]=ss;
  __syncthreads();
  float tot=red[0]+red[1]+red[2]+red[3];
  float rs=rsqrtf(tot*(1.f/2048.f)+1e-5f);
  for(int i=0;i<8;i++){ int c=threadIdx.x+i*256; yb16[(size_t)r*2048+c]=f2bf(v[i]*rs*w[c]); }
}

// ---------------- scorer stage 2: sigmoid(relu(h1) @ w2); h1 rows stride 384 ----------------
__global__ void k_scorer2(const float* __restrict__ h1, const float* __restrict__ w2, float* __restrict__ scores){
  int r = blockIdx.x; int lane = threadIdx.x; // 64 threads
  float s=0.f;
  for(int k=0;k<4;k++){ int c=lane+k*64; s += fmaxf(h1[(size_t)r*384+c],0.f)*w2[c]; }
  for(int off=32;off;off>>=1) s += __shfl_down(s,off,64);
  if(lane==0) scores[r]=sigmoidf_(s);
}

// ---------------- pool: parallel top-50 via float-bit bisection; exact-seq fallback on boundary tie ----------------
__global__ void k_pool(const float* __restrict__ scores,
                       int* __restrict__ countws, int* __restrict__ winners, float* __restrict__ condf){
  __shared__ float scs[BT];
  int lane = threadIdx.x;  // 64 threads
  float own[32];
  float ssum = 0.f; int vcnt = 0;
  #pragma unroll
  for(int i=0;i<32;i++){
    float s0 = scores[i*64 + lane];
    own[i] = s0; scs[i*64+lane] = s0;
    ssum += s0; vcnt += (s0 > 0.5f) ? 1 : 0;
  }
  float ts = ssum; int tv = vcnt;
  for(int off=32;off;off>>=1){ ts += __shfl_xor(ts,off,64); tv += __shfl_xor(tv,off,64); }
  int count = tv < POOL_N ? tv : POOL_N;
  bool fallback = false;
  if(tv <= POOL_N){
    int base = 0;
    #pragma unroll
    for(int i=0;i<32;i++){
      bool sel = own[i] > 0.5f;
      unsigned long long mask = __ballot(sel);
      int pre = __popcll(mask & ((1ull<<lane)-1ull));
      if(sel) winners[base + pre] = i*64 + lane;
      base += __popcll(mask);
    }
    for(int r=base+lane; r<POOL_N; r+=64) winners[r] = -1;
  } else {
    unsigned lo = 0u, hi = 0x3F800000u;
    while(hi - lo > 1u){
      unsigned mid = (lo + hi) >> 1;
      float midf = __uint_as_float(mid);
      int cnt = 0;
      #pragma unroll
      for(int i=0;i<32;i++) cnt += (own[i] >= midf) ? 1 : 0;
      for(int off=32;off;off>>=1) cnt += __shfl_xor(cnt,off,64);
      if(cnt >= POOL_N) lo = mid; else hi = mid;
    }
    float v50 = __uint_as_float(lo);
    int cl = 0;
    #pragma unroll
    for(int i=0;i<32;i++) cl += (own[i] >= v50) ? 1 : 0;
    for(int off=32;off;off>>=1) cl += __shfl_xor(cl,off,64);
    if(cl == POOL_N){
      int base = 0;
      #pragma unroll
      for(int i=0;i<32;i++){
        bool sel = own[i] >= v50;
        unsigned long long mask = __ballot(sel);
        int pre = __popcll(mask & ((1ull<<lane)-1ull));
        if(sel) winners[base + pre] = i*64 + lane;
        base += __popcll(mask);
      }
    } else fallback = true;
  }
  if(fallback){
    float prio = 0.f; int winner = -1; int cnt2 = 0;
    float curmin = 0.f; int curargmin = 0;
    for(int b0=0;b0<BT;b0+=64){
      float ow = scs[b0+lane];
      unsigned long long mask = (cnt2 < POOL_N) ? __ballot(ow > 0.5f) : __ballot(ow > curmin);
      while(mask){
        int j = __ffsll(mask) - 1;
        mask &= mask - 1ull;
        float sc = __shfl(ow, j, 64);
        if(cnt2 < POOL_N){
          if(lane == cnt2){ prio = sc; winner = b0+j; }
          cnt2++;
          if(cnt2 == POOL_N){
            float v = (lane < POOL_N)? prio : INFINITY; int idx = lane;
            for(int off=32;off;off>>=1){
              float ov = __shfl_xor(v,off,64); int oi = __shfl_xor(idx,off,64);
              if(ov < v || (ov==v && oi<idx)){ v=ov; idx=oi; }
            }
            curmin = v; curargmin = idx;
          }
        } else if(sc > curmin){
          if(lane == curargmin){ prio = sc; winner = b0+j; }
          float v = (lane < POOL_N)? prio : INFINITY; int idx = lane;
          for(int off=32;off;off>>=1){
            float ov = __shfl_xor(v,off,64); int oi = __shfl_xor(idx,off,64);
            if(ov < v || (ov==v && oi<idx)){ v=ov; idx=oi; }
          }
          curmin = v; curargmin = idx;
        }
      }
    }
    if(lane < POOL_N) winners[lane] = winner;
  }
  if(lane==0){
    countws[0] = count;
    float mean = ts*(1.f/2048.f);
    condf[0] = (mean>0.3f && count>0)? 1.f : 0.f;
  }
}

// ---------------- gather pool rows from hsq (stride 384, cols 256..319) ----------------
__global__ void k_poolg(const float* __restrict__ hsq, const int* __restrict__ winners, float* __restrict__ poolb){
  int p = blockIdx.x; int lane = threadIdx.x;
  int wi = winners[p];
  poolb[p*64+lane] = (wi>=0)? hsq[(size_t)wi*384 + 256 + lane] : 0.f;
}

// ---------------- kkT[j*64+p] = (pool @ k_w)[p][j] ----------------
__global__ void k_kk(const float* __restrict__ pool, const float* __restrict__ k_w, float* __restrict__ kkT){
  int o = blockIdx.x*256+threadIdx.x;
  if(o >= 64*POOL_N) return;
  int j = o/POOL_N, p = o%POOL_N;
  float s=0.f;
  for(int k=0;k<64;k++) s += pool[p*64+k]*k_w[k*64+j];
  kkT[j*64+p]=s;
}

// ---------------- vvT[d][p] bf16 = (pool @ v_w)[p][d]; cols p>=POOL_N zeroed ----------------
__global__ void k_vvT(const float* __restrict__ pool, const float* __restrict__ v_w, ushort* __restrict__ vvT){
  int o = blockIdx.x*256+threadIdx.x;  // 1024*64
  if(o >= 1024*64) return;
  int d = o>>6, p = o&63;
  float s=0.f;
  if(p < POOL_N)
    for(int k=0;k<64;k++) s += pool[p*64+k]*v_w[(size_t)k*1024+d];
  vvT[o] = f2bf(s);
}

// ---------------- probs: softmax(q·kkT/4, masked) -> Pb bf16 [2048][64]; q from hsq cols 320..383 ----------------
__global__ __launch_bounds__(256) void k_probs(const float* __restrict__ hsq, const float* __restrict__ kkT,
    const int* __restrict__ counti, ushort* __restrict__ Pb){
  __shared__ float qs[4][64];
  int tid = threadIdx.x;
  int w = tid>>6, lane = tid&63;
  int r = blockIdx.x*4 + w;
  qs[w][lane] = hsq[(size_t)r*384 + 320 + lane];
  __syncthreads();
  int count = counti[0];
  float logit = -1e9f;
  if(lane < POOL_N && lane < count){
    float s=0.f;
    for(int k=0;k<64;k++) s += qs[w][k]*kkT[k*64+lane];
    logit = s*0.25f;
  }
  float m = logit;
  for(int off=32;off;off>>=1) m = fmaxf(m, __shfl_xor(m,off,64));
  float e = expf(logit-m);
  float sum = e;
  for(int off=32;off;off>>=1) sum += __shfl_xor(sum,off,64);
  Pb[(size_t)r*64 + lane] = f2bf(e/sum);
}

// ---------------- PV: retr = Pb @ vvT^T (f32 + bf16 copies) ----------------
__global__ __launch_bounds__(256) void k_pv(const ushort* __restrict__ Pb, const ushort* __restrict__ vvT,
    float* __restrict__ retr, ushort* __restrict__ retrb){
  __shared__ __align__(16) ushort As[128*64];
  __shared__ __align__(16) ushort Bs[128*64];
  int m0 = (blockIdx.x >> 3)*128, n0 = (blockIdx.x & 7)*128;
  int tid = threadIdx.x;
  int row = tid>>1, half = tid&1;
  {
    const uint4* sa = (const uint4*)(Pb  + (size_t)(m0+row)*64 + half*32);
    const uint4* sb = (const uint4*)(vvT + (size_t)(n0+row)*64 + half*32);
    for(int ch=0;ch<4;ch++){
      int boff = (row<<7) + (half<<6) + (ch<<4);
      int so = boff ^ ((row&7)<<4);
      *(uint4*)((char*)As + so) = sa[ch];
      *(uint4*)((char*)Bs + so) = sb[ch];
    }
  }
  __syncthreads();
  int w=tid>>6, lane=tid&63, fr=lane&15, fq=lane>>4;
  int wr=(w>>1)*64, wc=(w&1)*64;
  f32x4 acc[4][4];
  for(int i=0;i<4;i++)for(int j=0;j<4;j++)acc[i][j]=(f32x4){0.f,0.f,0.f,0.f};
  for(int k0=0;k0<64;k0+=32){
    short8 af[4], bf_[4];
    for(int i=0;i<4;i++){
      int r = wr+i*16+fr;
      int boff = ((r<<7) + ((k0+fq*8)<<1)) ^ ((r&7)<<4);
      af[i] = *(const short8*)((char*)As + boff);
    }
    for(int j=0;j<4;j++){
      int r = wc+j*16+fr;
      int boff = ((r<<7) + ((k0+fq*8)<<1)) ^ ((r&7)<<4);
      bf_[j] = *(const short8*)((char*)Bs + boff);
    }
    for(int i=0;i<4;i++)
      for(int j=0;j<4;j++)
        acc[i][j] = __builtin_amdgcn_mfma_f32_16x16x32_bf16(af[i], bf_[j], acc[i][j], 0,0,0);
  }
  int rbase = m0 + wr + fq*4;
  for(int i=0;i<4;i++){
    for(int j=0;j<4;j++){
      int col = n0 + wc + j*16 + fr;
      for(int r=0;r<4;r++){
        float v = acc[i][j][r];
        size_t idx = (size_t)(rbase + i*16 + r)*1024 + col;
        retr[idx] = v;
        retrb[idx] = f2bf(v);
      }
    }
  }
}

static inline void gemmb(hipStream_t s, const ushort*A,const ushort*Bt,float*C,ushort*Cb,int M,int N,int K,int act){
  int nbx = (N+127)/128;
  int nwg = nbx * (M/128);
  hipLaunchKernelGGL(gemm_bf16,dim3(nwg),dim3(256),0,s,A,Bt,C,Cb,M,N,K,act,nbx);
}
static inline void gemmb64(hipStream_t s, const ushort*A,const ushort*Bt,float*C,ushort*Cb,int M,int N,int K,int act){
  int nbx = (N+127)/128;
  int nwg = nbx * (M/64);
  hipLaunchKernelGGL(gemm_bf16_64,dim3(nwg),dim3(256),0,s,A,Bt,C,Cb,M,N,K,act,nbx);
}

extern "C" void kernel_launch(void* const* d_in, const int* in_sizes, int n_in,
                              void* d_out, int out_size, void* d_ws, size_t ws_size,
                              hipStream_t stream) {
  const float* x        = (const float*)d_in[0];
  const float* norm_w   = (const float*)d_in[1];
  const float* in_proj_w= (const float*)d_in[2];
  const float* conv_w   = (const float*)d_in[3];
  const float* conv_b   = (const float*)d_in[4];
  const float* dt_bias  = (const float*)d_in[5];
  const float* A_log    = (const float*)d_in[6];
  const float* Dp       = (const float*)d_in[7];
  const float* ssm_norm_w=(const float*)d_in[8];
  const float* out_proj_w=(const float*)d_in[9];
  const float* scorer_w1= (const float*)d_in[10];
  const float* scorer_w2= (const float*)d_in[11];
  const float* summ_w   = (const float*)d_in[12];
  const float* q_w      = (const float*)d_in[13];
  const float* k_w      = (const float*)d_in[14];
  const float* v_w      = (const float*)d_in[15];
  const float* gate_w   = (const float*)d_in[16];
  float* out = (float*)d_out;

  unsigned char* base = (unsigned char*)d_ws;
  size_t off = 0;
  auto FB = [&](size_t bytes)->void*{ void* p = base+off; off = (off+bytes+255)&~(size_t)255; return p; };
  float* zxb   = (float*)FB((size_t)2048*D_IN_PROJ*4);
  float* dtb   = (float*)FB((size_t)2048*32*4);
  float* xbc   = (float*)FB((size_t)2048*CONV_DIM*4);
  float* csb   = (float*)FB((size_t)256*256*4);
  float* sdA   = (float*)FB(1024);
  float* states= (float*)FB((size_t)256*8192*4);
  float* prevb = (float*)FB((size_t)256*8192*4);
  float* ybuf  = (float*)FB((size_t)2048*2048*4);
  float* yout  = (float*)FB((size_t)2048*1024*4);
  float* scores= (float*)FB(2048*4);
  float* summ  = (float*)FB((size_t)2048*64*4);
  float* qb    = (float*)FB((size_t)2048*64*4);
  float* poolb = (float*)FB(POOL_N*64*4);
  float* prios = (float*)FB(256);
  float* miscf = (float*)FB(256);
  int*   counti= (int*)FB(256);
  int*   winners=(int*)FB(256);
  unsigned char* RX = (unsigned char*)FB((size_t)4194304);
  unsigned char* W1 = (unsigned char*)FB((size_t)8978432);

  ushort* xnb   = (ushort*)RX;
  ushort* scsqT = (ushort*)RX;                  // [384][1024] bf16
  float*  hsq   = (float*) (RX + 786432);       // [2048][384] f32
  float*  kkT   = (float*) ((unsigned char*)qb + 262144);
  ushort* vvT   = (ushort*)summ;
  ushort* Pb    = (ushort*)qb;
  ushort* inT   = (ushort*)W1;
  ushort* outT  = (ushort*)W1;
  ushort* gateT = (ushort*)(W1 + 4194304);
  float*  Gt    = yout;
  ushort* ybf   = (ushort*)prevb;
  float*  retr  = states;
  ushort* retrb = (ushort*)ybuf;
  ushort* youtb = (ushort*)((unsigned char*)ybuf + 8388608);
  (void)prios;

  hipLaunchKernelGGL(k_transpose_cvt, dim3(137,32), dim3(256), 0, stream, in_proj_w, inT, 1024, 4384);
  k_rmsnorm_x<<<2048,256,0,stream>>>(x, norm_w, xnb);
  gemmb(stream, xnb, inT, zxb, nullptr, 2048, D_IN_PROJ, 1024, 0);
  hipLaunchKernelGGL(k_transpose_cvt, dim3(32,64), dim3(256), 0, stream, out_proj_w, outT, 2048, 1024);
  hipLaunchKernelGGL(k_transpose_cvt, dim3(32,64), dim3(256), 0, stream, gate_w, gateT, 2048, 1024);
  hipLaunchKernelGGL(k_transpose_cvt, dim3(8,32), dim3(256), 0, stream, scorer_w1, scsqT, 1024, 256);
  hipLaunchKernelGGL(k_transpose_cvt, dim3(2,32), dim3(256), 0, stream, summ_w, scsqT + 256*1024, 1024, 64);
  hipLaunchKernelGGL(k_transpose_cvt, dim3(2,32), dim3(256), 0, stream, q_w, scsqT + 320*1024, 1024, 64);
  k_conv4<<<4864,256,0,stream>>>(zxb, conv_w, conv_b, xbc, dt_bias, dtb);
  k_gt<<<2048,256,0,stream>>>(xbc, Gt);
  k_ssd1w<<<256,512,0,stream>>>(xbc, dtb, A_log, Gt, ybuf, states, csb, sdA);
  k_ssd2<<<2048,256,0,stream>>>(states, sdA, prevb);
  k_ssd3m<<<256,256,0,stream>>>(xbc, csb, prevb, Dp, ybuf);
  k_gate_norm<<<2048,256,0,stream>>>(ybuf, zxb, ssm_norm_w, ybf);
  gemmb64(stream, ybf, outT, yout, youtb, 2048, 1024, 2048, 0);
  gemmb64(stream, youtb, scsqT, hsq, nullptr, 2048, 384, 1024, 0);
  k_scorer2<<<2048,64,0,stream>>>(hsq, scorer_w2, scores);
  k_pool<<<1,64,0,stream>>>(scores, counti, winners, miscf);
  k_poolg<<<POOL_N,64,0,stream>>>(hsq, winners, poolb);
  k_kk<<<(64*POOL_N+255)/256,256,0,stream>>>(poolb, k_w, kkT);
  k_vvT<<<256,256,0,stream>>>(poolb, v_w, vvT);
  k_probs<<<512,256,0,stream>>>(hsq, kkT, counti, Pb);
  k_pv<<<128,256,0,stream>>>(Pb, vvT, retr, retrb);
  hipLaunchKernelGGL(gemm_gate64, dim3(256), dim3(256), 0, stream,
                     youtb, retrb, gateT, x, yout, retr, miscf, out);
  (void)in_sizes; (void)n_in; (void)out_size; (void)ws_size;
}

// Round 19
// 271.279 us; speedup vs baseline: 1.0445x; 1.0038x over previous
//
#include <hip/hip_runtime.h>
#include <math.h>

#define NHEADS 32
#define D_INNER 2048
#define CONV_DIM 2304
#define D_IN_PROJ 4384
#define POOL_N 50
#define BT 2048

typedef __attribute__((ext_vector_type(8))) short short8;
typedef __attribute__((ext_vector_type(4))) float f32x4;

__device__ __forceinline__ float sigmoidf_(float x){ return 1.f/(1.f+expf(-x)); }
__device__ __forceinline__ ushort f2bf(float f){
  union{float f; unsigned u;} v; v.f=f;
  unsigned r = v.u + 0x7fffu + ((v.u>>16)&1u);
  return (ushort)(r>>16);
}
__device__ __forceinline__ void gload16(const void* g, void* l){
  __builtin_amdgcn_global_load_lds(
    (const __attribute__((address_space(1))) unsigned int*)g,
    (__attribute__((address_space(3))) unsigned int*)l, 16, 0, 0);
}

// ---------------- prep: blocks [0,4384) transpose in_proj_w -> inT bf16; [4384,6432) rmsnorm rows ----------------
__global__ __launch_bounds__(256) void k_prep(const float* __restrict__ ipw, ushort* __restrict__ inT,
    const float* __restrict__ x, const float* __restrict__ nw, ushort* __restrict__ xn){
  int b = blockIdx.x;
  if(b < 4384){
    __shared__ float tile[32][33];
    int bx = b % 137, by = b / 137;
    int c0 = bx*32, r0 = by*32;
    int tx = threadIdx.x&31, ty = threadIdx.x>>5;
    for(int i=0;i<4;i++){ int r = r0+ty+i*8; tile[ty+i*8][tx] = ipw[(size_t)r*4384 + c0+tx]; }
    __syncthreads();
    for(int i=0;i<4;i++){ int c = c0+ty+i*8; inT[(size_t)c*1024 + r0+tx] = f2bf(tile[tx][ty+i*8]); }
    return;
  }
  int r = b - 4384;
  const float* xr = x + (size_t)r*1024;
  float v[4]; float ss=0.f;
  for(int i=0;i<4;i++){ v[i]=xr[threadIdx.x+i*256]; ss+=v[i]*v[i]; }
  __shared__ float red[4];
  for(int off=32;off;off>>=1) ss += __shfl_down(ss,off,64);
  int wid=threadIdx.x>>6, lane=threadIdx.x&63;
  if(lane==0) red[wid]=ss;
  __syncthreads();
  float tot=red[0]+red[1]+red[2]+red[3];
  float rs=rsqrtf(tot*(1.f/1024.f)+1e-5f);
  for(int i=0;i<4;i++){ int c=threadIdx.x+i*256; xn[(size_t)r*1024+c]=f2bf(v[i]*rs*nw[c]); }
}

// ---------------- merged 5-way transpose+cvt (post in_proj GEMM) ----------------
__global__ __launch_bounds__(256) void k_transpose5(
    const float* __restrict__ s1, ushort* __restrict__ d1,   // out_proj 2048x1024
    const float* __restrict__ s2, ushort* __restrict__ d2,   // gate 2048x1024
    const float* __restrict__ s3, ushort* __restrict__ d3,   // scorer_w1 1024x256
    const float* __restrict__ s4, ushort* __restrict__ d4,   // summ 1024x64
    const float* __restrict__ s5, ushort* __restrict__ d5){  // q 1024x64
  int b = blockIdx.x;
  const float* src; ushort* dst; int R, C, bx, by;
  if(b < 2048){ src=s1; dst=d1; R=2048; C=1024; bx=b%32; by=b/32; }
  else if(b < 4096){ int t=b-2048; src=s2; dst=d2; R=2048; C=1024; bx=t%32; by=t/32; }
  else if(b < 4352){ int t=b-4096; src=s3; dst=d3; R=1024; C=256; bx=t%8; by=t/8; }
  else if(b < 4416){ int t=b-4352; src=s4; dst=d4; R=1024; C=64; bx=t%2; by=t/2; }
  else { int t=b-4416; src=s5; dst=d5; R=1024; C=64; bx=t%2; by=t/2; }
  __shared__ float tile[32][33];
  int c0 = bx*32, r0 = by*32;
  int tx = threadIdx.x&31, ty = threadIdx.x>>5;
  for(int i=0;i<4;i++){ int r = r0+ty+i*8; tile[ty+i*8][tx] = src[(size_t)r*C + c0+tx]; }
  __syncthreads();
  for(int i=0;i<4;i++){ int c = c0+ty+i*8; dst[(size_t)c*R + r0+tx] = f2bf(tile[tx][ty+i*8]); }
}

// ---------------- bf16 MFMA GEMM (BM=128): BK=64, dbuf LDS, counted vmcnt, XOR-swizzled ----------------
__global__ __launch_bounds__(256) void gemm_bf16(const ushort* __restrict__ A, const ushort* __restrict__ Bt,
    float* __restrict__ C, ushort* __restrict__ Cb, int M, int N, int K, int act, int nbx){
  __shared__ __align__(16) ushort As[2][128*64];
  __shared__ __align__(16) ushort Bs[2][128*64];
  int wg = blockIdx.x, nwg = gridDim.x;
  if((nwg & 7)==0){ int cpx = nwg>>3; wg = (wg&7)*cpx + (wg>>3); }
  int bx = wg % nbx, by = wg / nbx;
  int n0 = bx*128, m0 = by*128;
  int tid = threadIdx.x;
  int lane = tid&63, w = tid>>6;
  int wr = (w>>1)*64, wc = (w&1)*64;
  f32x4 acc[4][4];
  for(int i=0;i<4;i++)for(int j=0;j<4;j++)acc[i][j]=(f32x4){0.f,0.f,0.f,0.f};
  int col16s = (tid&7) ^ ((tid>>3)&7);
  int r0t = tid>>3;
  const char* AG[4]; const char* BG[4];
  #pragma unroll
  for(int c=0;c<4;c++){
    int r = r0t + c*32;
    AG[c] = (const char*)(A + (size_t)(m0+r)*K + col16s*8);
    int br = n0 + r;
    BG[c] = (const char*)(Bt + (size_t)((br<N)?br:0)*K + col16s*8);
  }
  int nk = K >> 6;
  int fr = lane&15, fq = lane>>4;
  {
    #pragma unroll
    for(int c=0;c<4;c++){
      gload16(AG[c], (char*)As[0] + (c*256 + w*64)*16);
      gload16(BG[c], (char*)Bs[0] + (c*256 + w*64)*16);
    }
  }
  for(int ks=0; ks<nk; ks++){
    int cur = ks&1;
    if(ks+1 < nk){
      size_t kb = (size_t)(ks+1)*128;
      #pragma unroll
      for(int c=0;c<4;c++){
        gload16(AG[c]+kb, (char*)As[cur^1] + (c*256 + w*64)*16);
        gload16(BG[c]+kb, (char*)Bs[cur^1] + (c*256 + w*64)*16);
      }
      asm volatile("s_waitcnt vmcnt(8)" ::: "memory");
    } else {
      asm volatile("s_waitcnt vmcnt(0)" ::: "memory");
    }
    __builtin_amdgcn_s_barrier();
    __builtin_amdgcn_sched_barrier(0);
    #pragma unroll
    for(int kk=0;kk<2;kk++){
      short8 af[4], bfr[4];
      #pragma unroll
      for(int i=0;i<4;i++){
        int rl = wr+i*16+fr;
        int off = ((rl<<7) + (kk<<6) + (fq<<4)) ^ ((rl&7)<<4);
        af[i] = *(const short8*)((char*)As[cur] + off);
      }
      #pragma unroll
      for(int j=0;j<4;j++){
        int rl = wc+j*16+fr;
        int off = ((rl<<7) + (kk<<6) + (fq<<4)) ^ ((rl&7)<<4);
        bfr[j] = *(const short8*)((char*)Bs[cur] + off);
      }
      #pragma unroll
      for(int i=0;i<4;i++)
        #pragma unroll
        for(int j=0;j<4;j++)
          acc[i][j] = __builtin_amdgcn_mfma_f32_16x16x32_bf16(af[i], bfr[j], acc[i][j], 0,0,0);
    }
    asm volatile("s_waitcnt lgkmcnt(0)" ::: "memory");
    __builtin_amdgcn_sched_barrier(0);
    __builtin_amdgcn_s_barrier();
  }
  int rbase = m0 + wr + fq*4;
  for(int i=0;i<4;i++){
    for(int j=0;j<4;j++){
      int col = n0 + wc + j*16 + fr;
      if(col < N){
        for(int r=0;r<4;r++){
          float v = acc[i][j][r];
          if(act) v = fmaxf(v,0.f);
          size_t idx = (size_t)(rbase + i*16 + r)*N + col;
          C[idx] = v;
          if(Cb) Cb[idx] = f2bf(v);
        }
      }
    }
  }
}

// ---------------- bf16 MFMA GEMM (BM=64): for M=2048,N<=1024 shapes (grid doubling) ----------------
__global__ __launch_bounds__(256) void gemm_bf16_64(const ushort* __restrict__ A, const ushort* __restrict__ Bt,
    float* __restrict__ C, ushort* __restrict__ Cb, int M, int N, int K, int act, int nbx){
  __shared__ __align__(16) ushort As[2][64*64];
  __shared__ __align__(16) ushort Bs[2][128*64];
  int wg = blockIdx.x, nwg = gridDim.x;
  if((nwg & 7)==0){ int cpx = nwg>>3; wg = (wg&7)*cpx + (wg>>3); }
  int bx = wg % nbx, by = wg / nbx;
  int n0 = bx*128, m0 = by*64;
  int tid = threadIdx.x;
  int lane = tid&63, w = tid>>6;
  f32x4 acc[4][2];
  for(int i=0;i<4;i++)for(int j=0;j<2;j++)acc[i][j]=(f32x4){0.f,0.f,0.f,0.f};
  int col16s = (tid&7) ^ ((tid>>3)&7);
  int r0t = tid>>3;
  const char* AG[2]; const char* BG[4];
  #pragma unroll
  for(int c=0;c<2;c++){
    int r = r0t + c*32;
    AG[c] = (const char*)(A + (size_t)(m0+r)*K + col16s*8);
  }
  #pragma unroll
  for(int c=0;c<4;c++){
    int br = n0 + r0t + c*32;
    BG[c] = (const char*)(Bt + (size_t)((br<N)?br:0)*K + col16s*8);
  }
  int nk = K >> 6;
  int fr = lane&15, fq = lane>>4;
  {
    #pragma unroll
    for(int c=0;c<2;c++) gload16(AG[c], (char*)As[0] + (c*256 + w*64)*16);
    #pragma unroll
    for(int c=0;c<4;c++) gload16(BG[c], (char*)Bs[0] + (c*256 + w*64)*16);
  }
  for(int ks=0; ks<nk; ks++){
    int cur = ks&1;
    if(ks+1 < nk){
      size_t kb = (size_t)(ks+1)*128;
      #pragma unroll
      for(int c=0;c<2;c++) gload16(AG[c]+kb, (char*)As[cur^1] + (c*256 + w*64)*16);
      #pragma unroll
      for(int c=0;c<4;c++) gload16(BG[c]+kb, (char*)Bs[cur^1] + (c*256 + w*64)*16);
      asm volatile("s_waitcnt vmcnt(6)" ::: "memory");
    } else {
      asm volatile("s_waitcnt vmcnt(0)" ::: "memory");
    }
    __builtin_amdgcn_s_barrier();
    __builtin_amdgcn_sched_barrier(0);
    #pragma unroll
    for(int kk=0;kk<2;kk++){
      short8 af[4], bfr[2];
      #pragma unroll
      for(int i=0;i<4;i++){
        int rl = i*16+fr;
        int off = ((rl<<7) + (kk<<6) + (fq<<4)) ^ ((rl&7)<<4);
        af[i] = *(const short8*)((char*)As[cur] + off);
      }
      #pragma unroll
      for(int j=0;j<2;j++){
        int rl = w*32+j*16+fr;
        int off = ((rl<<7) + (kk<<6) + (fq<<4)) ^ ((rl&7)<<4);
        bfr[j] = *(const short8*)((char*)Bs[cur] + off);
      }
      #pragma unroll
      for(int i=0;i<4;i++)
        #pragma unroll
        for(int j=0;j<2;j++)
          acc[i][j] = __builtin_amdgcn_mfma_f32_16x16x32_bf16(af[i], bfr[j], acc[i][j], 0,0,0);
    }
    asm volatile("s_waitcnt lgkmcnt(0)" ::: "memory");
    __builtin_amdgcn_sched_barrier(0);
    __builtin_amdgcn_s_barrier();
  }
  int rbase = m0 + fq*4;
  for(int i=0;i<4;i++){
    for(int j=0;j<2;j++){
      int col = n0 + w*32 + j*16 + fr;
      if(col < N){
        for(int r=0;r<4;r++){
          float v = acc[i][j][r];
          if(act) v = fmaxf(v,0.f);
          size_t idx = (size_t)(rbase + i*16 + r)*N + col;
          C[idx] = v;
          if(Cb) Cb[idx] = f2bf(v);
        }
      }
    }
  }
}

// ---------------- gate GEMM (BM=64): A=[youtb|retrb] split at k=1024, fused final epilogue ----------------
__global__ __launch_bounds__(256) void gemm_gate64(const ushort* __restrict__ Ay, const ushort* __restrict__ Ar,
    const ushort* __restrict__ Bt, const float* __restrict__ x, const float* __restrict__ yout,
    const float* __restrict__ retr, const float* __restrict__ condf, float* __restrict__ out){
  __shared__ __align__(16) ushort As[2][64*64];
  __shared__ __align__(16) ushort Bs[2][128*64];
  const int nbx = 8;
  int wg = blockIdx.x, nwg = gridDim.x;
  if((nwg & 7)==0){ int cpx = nwg>>3; wg = (wg&7)*cpx + (wg>>3); }
  int bx = wg % nbx, by = wg / nbx;
  int n0 = bx*128, m0 = by*64;
  int tid = threadIdx.x;
  int lane = tid&63, w = tid>>6;
  f32x4 acc[4][2];
  for(int i=0;i<4;i++)for(int j=0;j<2;j++)acc[i][j]=(f32x4){0.f,0.f,0.f,0.f};
  int col16s = (tid&7) ^ ((tid>>3)&7);
  int r0t = tid>>3;
  const char* AGy[2]; const char* AGr[2]; const char* BG[4];
  #pragma unroll
  for(int c=0;c<2;c++){
    int r = r0t + c*32;
    AGy[c] = (const char*)(Ay + (size_t)(m0+r)*1024 + col16s*8);
    AGr[c] = (const char*)(Ar + (size_t)(m0+r)*1024 + col16s*8);
  }
  #pragma unroll
  for(int c=0;c<4;c++){
    int br = n0 + r0t + c*32;
    BG[c] = (const char*)(Bt + (size_t)br*2048 + col16s*8);
  }
  const int nk = 32;
  int fr = lane&15, fq = lane>>4;
  {
    #pragma unroll
    for(int c=0;c<2;c++) gload16(AGy[c], (char*)As[0] + (c*256 + w*64)*16);
    #pragma unroll
    for(int c=0;c<4;c++) gload16(BG[c],  (char*)Bs[0] + (c*256 + w*64)*16);
  }
  for(int ks=0; ks<nk; ks++){
    int cur = ks&1;
    if(ks+1 < nk){
      int t = ks+1;
      size_t kbA = (size_t)((t<16)? t : t-16)*128;
      size_t kbB = (size_t)t*128;
      #pragma unroll
      for(int c=0;c<2;c++){
        const char* asrc = (t<16) ? (AGy[c]+kbA) : (AGr[c]+kbA);
        gload16(asrc, (char*)As[cur^1] + (c*256 + w*64)*16);
      }
      #pragma unroll
      for(int c=0;c<4;c++) gload16(BG[c]+kbB, (char*)Bs[cur^1] + (c*256 + w*64)*16);
      asm volatile("s_waitcnt vmcnt(6)" ::: "memory");
    } else {
      asm volatile("s_waitcnt vmcnt(0)" ::: "memory");
    }
    __builtin_amdgcn_s_barrier();
    __builtin_amdgcn_sched_barrier(0);
    #pragma unroll
    for(int kk=0;kk<2;kk++){
      short8 af[4], bfr[2];
      #pragma unroll
      for(int i=0;i<4;i++){
        int rl = i*16+fr;
        int off = ((rl<<7) + (kk<<6) + (fq<<4)) ^ ((rl&7)<<4);
        af[i] = *(const short8*)((char*)As[cur] + off);
      }
      #pragma unroll
      for(int j=0;j<2;j++){
        int rl = w*32+j*16+fr;
        int off = ((rl<<7) + (kk<<6) + (fq<<4)) ^ ((rl&7)<<4);
        bfr[j] = *(const short8*)((char*)Bs[cur] + off);
      }
      #pragma unroll
      for(int i=0;i<4;i++)
        #pragma unroll
        for(int j=0;j<2;j++)
          acc[i][j] = __builtin_amdgcn_mfma_f32_16x16x32_bf16(af[i], bfr[j], acc[i][j], 0,0,0);
    }
    asm volatile("s_waitcnt lgkmcnt(0)" ::: "memory");
    __builtin_amdgcn_sched_barrier(0);
    __builtin_amdgcn_s_barrier();
  }
  float cond = condf[0];
  int rbase = m0 + fq*4;
  for(int i=0;i<4;i++){
    for(int j=0;j<2;j++){
      int col = n0 + w*32 + j*16 + fr;
      for(int r=0;r<4;r++){
        size_t idx = (size_t)(rbase + i*16 + r)*1024 + col;
        float gv = sigmoidf_(acc[i][j][r]);
        out[idx] = x[idx] + yout[idx] + cond*gv*retr[idx];
      }
    }
  }
}

// ---------------- causal depthwise conv (k=4) + silu, 4 channels/thread; tail blocks do dt softplus ----------------
__global__ void k_conv4(const float* __restrict__ zxb, const float* __restrict__ cw, const float* __restrict__ cb,
                        float* __restrict__ xbc, const float* __restrict__ dt_bias, float* __restrict__ dtb){
  int o = blockIdx.x*256+threadIdx.x;
  if(o >= 2048*576){
    int o2 = o - 2048*576;    // 0 .. 65535: dt = softplus(zxb[:, -32:] + bias)
    int r = o2>>5, h = o2&31;
    float v = zxb[(size_t)r*D_IN_PROJ + 4352 + h] + dt_bias[h];
    dtb[o2] = (v>20.f) ? v : log1pf(expf(v));
    return;
  }
  int ch4 = (o % 576)*4; int rt = o / 576;
  int b = rt>>10, t = rt&1023;
  float a[4];
  { float4 cbv = *(const float4*)(cb + ch4); a[0]=cbv.x; a[1]=cbv.y; a[2]=cbv.z; a[3]=cbv.w; }
  float cwa[4][4];
  for(int c2=0;c2<4;c2++){
    float4 v = *(const float4*)(cw + (ch4+c2)*4);
    cwa[c2][0]=v.x; cwa[c2][1]=v.y; cwa[c2][2]=v.z; cwa[c2][3]=v.w;
  }
  for(int k=0;k<4;k++){
    int tt = t-3+k;
    if(tt>=0){
      float4 v = *(const float4*)(zxb + (size_t)(b*1024+tt)*D_IN_PROJ + 2048 + ch4);
      a[0] += v.x*cwa[0][k]; a[1] += v.y*cwa[1][k];
      a[2] += v.z*cwa[2][k]; a[3] += v.w*cwa[3][k];
    }
  }
  float4 o4;
  o4.x = a[0]*sigmoidf_(a[0]); o4.y = a[1]*sigmoidf_(a[1]);
  o4.z = a[2]*sigmoidf_(a[2]); o4.w = a[3]*sigmoidf_(a[3]);
  *(float4*)(xbc + (size_t)rt*CONV_DIM + ch4) = o4;
}

// ---------------- G^T per (b,c): Gt[s*256+l] = dot(C[l], B[s]) ----------------
__global__ __launch_bounds__(256) void k_gt(const float* __restrict__ xbc, float* __restrict__ Gt){
  int bc = blockIdx.x >> 8;
  int tile = blockIdx.x & 255;
  int l0 = (tile>>4)<<4, s0 = (tile&15)<<4;
  int b = bc>>2, c = bc&3;
  int row0 = b*1024 + c*256;
  __shared__ float Cs[16][130], Bs2[16][130];
  int tid = threadIdx.x;
  for(int i=0;i<8;i++){ int e=tid+i*256; int rr=e>>7, n=e&127;
    Cs[rr][n]  = xbc[(size_t)(row0+l0+rr)*CONV_DIM + 2176 + n];
    Bs2[rr][n] = xbc[(size_t)(row0+s0+rr)*CONV_DIM + 2048 + n];
  }
  __syncthreads();
  int tx = tid&15, ty = tid>>4;
  float acc=0.f;
  for(int n=0;n<128;n++) acc += Cs[tx][n]*Bs2[ty][n];
  Gt[(size_t)bc*65536 + (size_t)(s0+ty)*256 + (l0+tx)] = acc;
}

// ---------------- SSD per (b,c,h): 512 threads, wave-specialized ----------------
__global__ __launch_bounds__(512) void k_ssd1w(const float* __restrict__ xbc, const float* __restrict__ dtb,
    const float* __restrict__ A_log, const float* __restrict__ Gt,
    float* __restrict__ ybuf, float* __restrict__ states, float* __restrict__ csb, float* __restrict__ sdA){
  int blk = blockIdx.x;      // (b*4+c)*32+h
  int bc = blk>>5, h = blk&31;
  int b = bc>>2, c = bc&3;
  int row0 = b*1024 + c*256;
  int tid = threadIdx.x;
  __shared__ float cs[256];
  __shared__ float dts[256];
  __shared__ float dec[256];
  __shared__ __align__(16) ushort xdT[64*256];
  __shared__ __align__(16) ushort Mw[4*64*32];
  __shared__ __align__(16) ushort Bw[4*32*256];
  float Ah = -expf(A_log[h]);
  if(tid < 256){
    float dtv = dtb[(size_t)(row0+tid)*32 + h];
    dts[tid] = dtv;
    cs[tid] = dtv*Ah;
  }
  __syncthreads();
  for(int o=1;o<256;o<<=1){
    float add = 0.f;
    if(tid<256 && tid>=o) add = cs[tid-o];
    __syncthreads();
    if(tid<256) cs[tid] += add;
    __syncthreads();
  }
  float cslast = cs[255];
  if(tid < 256){
    float csl = cs[tid];
    csb[blk*256+tid] = csl;
    dec[tid] = expf(cslast - csl);
    if(tid==0) sdA[blk] = cslast;
  }
  {
    int p = tid&63, g = tid>>6;
    for(int i=0;i<32;i++){
      int l = g + 8*i;
      float v = xbc[(size_t)(row0+l)*CONV_DIM + h*64 + p] * dts[l];
      int off = ((p<<9) + (l<<1)) ^ ((p&7)<<4);
      *(ushort*)((char*)xdT + off) = f2bf(v);
    }
  }
  __syncthreads();

  int w = tid>>6, lane = tid&63;
  int fr = lane&15, fq = lane>>4;
  const float* gt = Gt + (size_t)bc*65536;
  if(w < 4){
    int rowl = w*64 + lane;
    float csl_w = cs[rowl];
    f32x4 accY[4][4];
    for(int i=0;i<4;i++)for(int j=0;j<4;j++)accY[i][j]=(f32x4){0.f,0.f,0.f,0.f};
    int nk = 2*(w+1);
    for(int ks=0; ks<nk; ks++){
      int s0 = ks*32;
      float cs_s0 = cs[s0];
      float ev = expf(cs_s0 - cs[s0 + (lane&31)]);
      float el = expf(csl_w - cs_s0);
      for(int j=0;j<4;j++){
        short8 mp;
        for(int k=0;k<8;k++){
          int s2 = j*8+k;
          int s = s0 + s2;
          float gv = gt[(size_t)s*256 + rowl];
          float esv = __shfl(ev, s2, 64);
          float m = (s <= rowl) ? gv*el*esv : 0.f;
          mp[k] = (short)f2bf(m);
        }
        int off = (w<<12) + ((((lane)<<6) + (j<<4)) ^ ((lane&7)<<4));
        *(short8*)((char*)Mw + off) = mp;
      }
      asm volatile("s_waitcnt lgkmcnt(0)" ::: "memory");
      __builtin_amdgcn_sched_barrier(0);
      short8 af[4], bv4[4];
      for(int i=0;i<4;i++){
        int lp = i*16 + fr;
        int off = (w<<12) + (((lp<<6) + (fq<<4)) ^ ((lp&7)<<4));
        af[i] = *(const short8*)((char*)Mw + off);
      }
      for(int j=0;j<4;j++){
        int p = j*16 + fr;
        int off = ((p<<9) + ((s0 + fq*8)<<1)) ^ ((p&7)<<4);
        bv4[j] = *(const short8*)((char*)xdT + off);
      }
      for(int i=0;i<4;i++)
        for(int j=0;j<4;j++)
          accY[i][j] = __builtin_amdgcn_mfma_f32_16x16x32_bf16(af[i], bv4[j], accY[i][j], 0,0,0);
      asm volatile("" ::: "memory");
    }
    for(int i=0;i<4;i++){
      int l = 64*w + i*16 + fq*4;
      for(int j=0;j<4;j++){
        int p = j*16 + fr;
        for(int r=0;r<4;r++)
          ybuf[(size_t)(row0+l+r)*2048 + h*64 + p] = accY[i][j][r];
      }
    }
  } else {
    int sw = w-4, nbase = sw*32;
    {
      int nn = lane&31, half = lane>>5;
      for(int i=0;i<128;i++){
        int l = half + 2*i;
        float v = xbc[(size_t)(row0+l)*CONV_DIM + 2048 + nbase + nn] * dec[l];
        int off = (sw<<14) + (((nn<<9) + (l<<1)) ^ ((nn&7)<<4));
        *(ushort*)((char*)Bw + off) = f2bf(v);
      }
    }
    asm volatile("s_waitcnt lgkmcnt(0)" ::: "memory");
    __builtin_amdgcn_sched_barrier(0);
    f32x4 accS[4][2];
    for(int i=0;i<4;i++)for(int j=0;j<2;j++)accS[i][j]=(f32x4){0.f,0.f,0.f,0.f};
    for(int ks=0;ks<8;ks++){
      int l0 = ks*32;
      short8 aS[4], bS[2];
      for(int i=0;i<4;i++){
        int p = i*16 + fr;
        int off = ((p<<9) + ((l0+fq*8)<<1)) ^ ((p&7)<<4);
        aS[i] = *(const short8*)((char*)xdT + off);
      }
      for(int j=0;j<2;j++){
        int nn = j*16 + fr;
        int off = (sw<<14) + (((nn<<9) + ((l0+fq*8)<<1)) ^ ((nn&7)<<4));
        bS[j] = *(const short8*)((char*)Bw + off);
      }
      for(int i=0;i<4;i++)
        for(int j=0;j<2;j++)
          accS[i][j] = __builtin_amdgcn_mfma_f32_16x16x32_bf16(aS[i], bS[j], accS[i][j], 0,0,0);
    }
    for(int i=0;i<4;i++){
      int p = i*16 + fq*4;
      for(int j=0;j<2;j++){
        int n = nbase + j*16 + fr;
        for(int r=0;r<4;r++)
          states[(size_t)blk*8192 + (size_t)(p+r)*128 + n] = accS[i][j][r];
      }
    }
  }
}

// ---------------- chunk scan over c=0..3 ----------------
__global__ __launch_bounds__(256) void k_ssd2(const float* __restrict__ states, const float* __restrict__ sdA, float* __restrict__ prevb){
  int idx = blockIdx.x*256 + threadIdx.x;
  int e = idx & 8191;
  int h = (idx >> 13) & 31;
  int b = idx >> 18;
  float run = 0.f;
  for(int c=0;c<4;c++){
    int sblk = (b*4+c)*32 + h;
    size_t base = (size_t)sblk*8192 + e;
    prevb[base] = run;
    run = (run + states[base]) * expf(sdA[sblk]);
  }
}

// ---------------- y_off = C @ prev^T via MFMA; += xs*D into ybuf ----------------
__global__ __launch_bounds__(256) void k_ssd3m(const float* __restrict__ xbc, const float* __restrict__ csb,
    const float* __restrict__ prevb, const float* __restrict__ Dp, float* __restrict__ ybuf){
  int blk = blockIdx.x; int bc = blk>>5, h = blk&31; int b=bc>>2, c=bc&3;
  int row0 = b*1024+c*256;
  int tid = threadIdx.x;
  __shared__ __align__(16) ushort Cs[256*128];
  __shared__ __align__(16) ushort Ps[64*128];
  __shared__ float cse[256];
  for(int i=0;i<128;i++){
    int id = tid + i*256;
    int n = id & 127, l = id >> 7;
    float v = xbc[(size_t)(row0+l)*CONV_DIM + 2176 + n];
    int off = ((l<<8) + (n<<1)) ^ ((l&7)<<4);
    *(ushort*)((char*)Cs + off) = f2bf(v);
  }
  for(int i=0;i<32;i++){
    int id = tid + i*256;
    int n = id & 127, p = id >> 7;
    float v = prevb[(size_t)blk*8192 + id];
    int off = ((p<<8) + (n<<1)) ^ ((p&7)<<4);
    *(ushort*)((char*)Ps + off) = f2bf(v);
  }
  cse[tid] = expf(csb[blk*256+tid]);
  __syncthreads();
  int w=tid>>6, lane=tid&63, fr=lane&15, fq=lane>>4;
  f32x4 acc[4][4];
  for(int i=0;i<4;i++)for(int j=0;j<4;j++)acc[i][j]=(f32x4){0.f,0.f,0.f,0.f};
  for(int ks=0;ks<4;ks++){
    int n0 = ks*32;
    short8 af[4], bf_[4];
    for(int i=0;i<4;i++){
      int l = w*64 + i*16 + fr;
      int off = ((l<<8) + ((n0+fq*8)<<1)) ^ ((l&7)<<4);
      af[i] = *(const short8*)((char*)Cs + off);
    }
    for(int j=0;j<4;j++){
      int p = j*16 + fr;
      int off = ((p<<8) + ((n0+fq*8)<<1)) ^ ((p&7)<<4);
      bf_[j] = *(const short8*)((char*)Ps + off);
    }
    for(int i=0;i<4;i++)
      for(int j=0;j<4;j++)
        acc[i][j] = __builtin_amdgcn_mfma_f32_16x16x32_bf16(af[i], bf_[j], acc[i][j], 0,0,0);
  }
  float Dh = Dp[h];
  for(int i=0;i<4;i++){
    int lbase = 64*w + i*16 + fq*4;
    for(int r=0;r<4;r++){
      int l = lbase + r;
      float e = cse[l];
      size_t rowoff = (size_t)(row0+l)*CONV_DIM + h*64;
      size_t yb = (size_t)(row0+l)*2048 + h*64;
      for(int j=0;j<4;j++){
        int p = j*16 + fr;
        float xs = xbc[rowoff + p];
        ybuf[yb+p] += e*acc[i][j][r] + xs*Dh;
      }
    }
  }
}

// ---------------- y = rmsnorm(y * silu(z)) -> bf16 (D=2048) ----------------
__global__ __launch_bounds__(256) void k_gate_norm(const float* __restrict__ y, const float* __restrict__ zxb,
    const float* __restrict__ w, ushort* __restrict__ yb16){
  int r = blockIdx.x;
  const float* zr = zxb + (size_t)r*D_IN_PROJ;
  const float* yr = y + (size_t)r*2048;
  float v[8]; float ss=0.f;
  for(int i=0;i<8;i++){ int c=threadIdx.x+i*256; float z=zr[c]; float g=yr[c]*(z*sigmoidf_(z)); v[i]=g; ss+=g*g; }
  __shared__ float red[4];
  for(int off=32;off;off>>=1) ss += __shfl_down(ss,off,64);
  int wid=threadIdx.x>>6, lane=threadIdx.x&63;
  if(lane==0) red[wid]=ss;
  __syncthreads();
  float tot=red[0]+red[1]+red[2]+red[3];
  float rs=rsqrtf(tot*(1.f/2048.f)+1e-5f);
  for(int i=0;i<8;i++){ int c=threadIdx.x+i*256; yb16[(size_t)r*2048+c]=f2bf(v[i]*rs*w[c]); }
}

// ---------------- scorer stage 2: sigmoid(relu(h1) @ w2); h1 rows stride 384 ----------------
__global__ void k_scorer2(const float* __restrict__ h1, const float* __restrict__ w2, float* __restrict__ scores){
  int r = blockIdx.x; int lane = threadIdx.x; // 64 threads
  float s=0.f;
  for(int k=0;k<4;k++){ int c=lane+k*64; s += fmaxf(h1[(size_t)r*384+c],0.f)*w2[c]; }
  for(int off=32;off;off>>=1) s += __shfl_down(s,off,64);
  if(lane==0) scores[r]=sigmoidf_(s);
}

// ---------------- pool: parallel top-50 (bisection, exact-seq fallback) + fused gather from hsq ----------------
__global__ void k_pool(const float* __restrict__ scores,
                       int* __restrict__ countws, float* __restrict__ condf,
                       const float* __restrict__ hsq, float* __restrict__ poolb){
  __shared__ float scs[BT];
  __shared__ int wsh[64];
  int lane = threadIdx.x;  // 64 threads
  float own[32];
  float ssum = 0.f; int vcnt = 0;
  #pragma unroll
  for(int i=0;i<32;i++){
    float s0 = scores[i*64 + lane];
    own[i] = s0; scs[i*64+lane] = s0;
    ssum += s0; vcnt += (s0 > 0.5f) ? 1 : 0;
  }
  float ts = ssum; int tv = vcnt;
  for(int off=32;off;off>>=1){ ts += __shfl_xor(ts,off,64); tv += __shfl_xor(tv,off,64); }
  int count = tv < POOL_N ? tv : POOL_N;
  bool fallback = false;
  if(tv <= POOL_N){
    int base = 0;
    #pragma unroll
    for(int i=0;i<32;i++){
      bool sel = own[i] > 0.5f;
      unsigned long long mask = __ballot(sel);
      int pre = __popcll(mask & ((1ull<<lane)-1ull));
      if(sel) wsh[base + pre] = i*64 + lane;
      base += __popcll(mask);
    }
    for(int r=base+lane; r<POOL_N; r+=64) wsh[r] = -1;
  } else {
    unsigned lo = 0u, hi = 0x3F800000u;
    while(hi - lo > 1u){
      unsigned mid = (lo + hi) >> 1;
      float midf = __uint_as_float(mid);
      int cnt = 0;
      #pragma unroll
      for(int i=0;i<32;i++) cnt += (own[i] >= midf) ? 1 : 0;
      for(int off=32;off;off>>=1) cnt += __shfl_xor(cnt,off,64);
      if(cnt >= POOL_N) lo = mid; else hi = mid;
    }
    float v50 = __uint_as_float(lo);
    int cl = 0;
    #pragma unroll
    for(int i=0;i<32;i++) cl += (own[i] >= v50) ? 1 : 0;
    for(int off=32;off;off>>=1) cl += __shfl_xor(cl,off,64);
    if(cl == POOL_N){
      int base = 0;
      #pragma unroll
      for(int i=0;i<32;i++){
        bool sel = own[i] >= v50;
        unsigned long long mask = __ballot(sel);
        int pre = __popcll(mask & ((1ull<<lane)-1ull));
        if(sel) wsh[base + pre] = i*64 + lane;
        base += __popcll(mask);
      }
    } else fallback = true;
  }
  if(fallback){
    float prio = 0.f; int winner = -1; int cnt2 = 0;
    float curmin = 0.f; int curargmin = 0;
    for(int b0=0;b0<BT;b0+=64){
      float ow = scs[b0+lane];
      unsigned long long mask = (cnt2 < POOL_N) ? __ballot(ow > 0.5f) : __ballot(ow > curmin);
      while(mask){
        int j = __ffsll(mask) - 1;
        mask &= mask - 1ull;
        float sc = __shfl(ow, j, 64);
        if(cnt2 < POOL_N){
          if(lane == cnt2){ prio = sc; winner = b0+j; }
          cnt2++;
          if(cnt2 == POOL_N){
            float v = (lane < POOL_N)? prio : INFINITY; int idx = lane;
            for(int off=32;off;off>>=1){
              float ov = __shfl_xor(v,off,64); int oi = __shfl_xor(idx,off,64);
              if(ov < v || (ov==v && oi<idx)){ v=ov; idx=oi; }
            }
            curmin = v; curargmin = idx;
          }
        } else if(sc > curmin){
          if(lane == curargmin){ prio = sc; winner = b0+j; }
          float v = (lane < POOL_N)? prio : INFINITY; int idx = lane;
          for(int off=32;off;off>>=1){
            float ov = __shfl_xor(v,off,64); int oi = __shfl_xor(idx,off,64);
            if(ov < v || (ov==v && oi<idx)){ v=ov; idx=oi; }
          }
          curmin = v; curargmin = idx;
        }
      }
    }
    if(lane < POOL_N) wsh[lane] = winner;
  }
  __syncthreads();
  // fused gather: poolb[p][lane] = hsq[wsh[p]*384 + 256 + lane]
  for(int p=0;p<POOL_N;p++){
    int wi = wsh[p];
    poolb[p*64+lane] = (wi>=0)? hsq[(size_t)wi*384 + 256 + lane] : 0.f;
  }
  if(lane==0){
    countws[0] = count;
    float mean = ts*(1.f/2048.f);
    condf[0] = (mean>0.3f && count>0)? 1.f : 0.f;
  }
}

// ---------------- fused kk + vvT: blocks [0,13) kk, [13,269) vvT ----------------
__global__ void k_kkvv(const float* __restrict__ pool, const float* __restrict__ k_w, float* __restrict__ kkT,
                       const float* __restrict__ v_w, ushort* __restrict__ vvT){
  if(blockIdx.x < 13){
    int o = blockIdx.x*256 + threadIdx.x;
    if(o >= 64*POOL_N) return;
    int j = o/POOL_N, p = o%POOL_N;
    float s=0.f;
    for(int k=0;k<64;k++) s += pool[p*64+k]*k_w[k*64+j];
    kkT[j*64+p]=s;
  } else {
    int o = (blockIdx.x-13)*256 + threadIdx.x;  // 0 .. 65535
    int d = o>>6, p = o&63;
    float s=0.f;
    if(p < POOL_N)
      for(int k=0;k<64;k++) s += pool[p*64+k]*v_w[(size_t)k*1024+d];
    vvT[o] = f2bf(s);
  }
}

// ---------------- probs: softmax(q·kkT/4, masked) -> Pb bf16 [2048][64]; q from hsq cols 320..383 ----------------
__global__ __launch_bounds__(256) void k_probs(const float* __restrict__ hsq, const float* __restrict__ kkT,
    const int* __restrict__ counti, ushort* __restrict__ Pb){
  __shared__ float qs[4][64];
  int tid = threadIdx.x;
  int w = tid>>6, lane = tid&63;
  int r = blockIdx.x*4 + w;
  qs[w][lane] = hsq[(size_t)r*384 + 320 + lane];
  __syncthreads();
  int count = counti[0];
  float logit = -1e9f;
  if(lane < POOL_N && lane < count){
    float s=0.f;
    for(int k=0;k<64;k++) s += qs[w][k]*kkT[k*64+lane];
    logit = s*0.25f;
  }
  float m = logit;
  for(int off=32;off;off>>=1) m = fmaxf(m, __shfl_xor(m,off,64));
  float e = expf(logit-m);
  float sum = e;
  for(int off=32;off;off>>=1) sum += __shfl_xor(sum,off,64);
  Pb[(size_t)r*64 + lane] = f2bf(e/sum);
}

// ---------------- PV: retr = Pb @ vvT^T (f32 + bf16 copies) ----------------
__global__ __launch_bounds__(256) void k_pv(const ushort* __restrict__ Pb, const ushort* __restrict__ vvT,
    float* __restrict__ retr, ushort* __restrict__ retrb){
  __shared__ __align__(16) ushort As[128*64];
  __shared__ __align__(16) ushort Bs[128*64];
  int m0 = (blockIdx.x >> 3)*128, n0 = (blockIdx.x & 7)*128;
  int tid = threadIdx.x;
  int row = tid>>1, half = tid&1;
  {
    const uint4* sa = (const uint4*)(Pb  + (size_t)(m0+row)*64 + half*32);
    const uint4* sb = (const uint4*)(vvT + (size_t)(n0+row)*64 + half*32);
    for(int ch=0;ch<4;ch++){
      int boff = (row<<7) + (half<<6) + (ch<<4);
      int so = boff ^ ((row&7)<<4);
      *(uint4*)((char*)As + so) = sa[ch];
      *(uint4*)((char*)Bs + so) = sb[ch];
    }
  }
  __syncthreads();
  int w=tid>>6, lane=tid&63, fr=lane&15, fq=lane>>4;
  int wr=(w>>1)*64, wc=(w&1)*64;
  f32x4 acc[4][4];
  for(int i=0;i<4;i++)for(int j=0;j<4;j++)acc[i][j]=(f32x4){0.f,0.f,0.f,0.f};
  for(int k0=0;k0<64;k0+=32){
    short8 af[4], bf_[4];
    for(int i=0;i<4;i++){
      int r = wr+i*16+fr;
      int boff = ((r<<7) + ((k0+fq*8)<<1)) ^ ((r&7)<<4);
      af[i] = *(const short8*)((char*)As + boff);
    }
    for(int j=0;j<4;j++){
      int r = wc+j*16+fr;
      int boff = ((r<<7) + ((k0+fq*8)<<1)) ^ ((r&7)<<4);
      bf_[j] = *(const short8*)((char*)Bs + boff);
    }
    for(int i=0;i<4;i++)
      for(int j=0;j<4;j++)
        acc[i][j] = __builtin_amdgcn_mfma_f32_16x16x32_bf16(af[i], bf_[j], acc[i][j], 0,0,0);
  }
  int rbase = m0 + wr + fq*4;
  for(int i=0;i<4;i++){
    for(int j=0;j<4;j++){
      int col = n0 + wc + j*16 + fr;
      for(int r=0;r<4;r++){
        float v = acc[i][j][r];
        size_t idx = (size_t)(rbase + i*16 + r)*1024 + col;
        retr[idx] = v;
        retrb[idx] = f2bf(v);
      }
    }
  }
}

static inline void gemmb(hipStream_t s, const ushort*A,const ushort*Bt,float*C,ushort*Cb,int M,int N,int K,int act){
  int nbx = (N+127)/128;
  int nwg = nbx * (M/128);
  hipLaunchKernelGGL(gemm_bf16,dim3(nwg),dim3(256),0,s,A,Bt,C,Cb,M,N,K,act,nbx);
}
static inline void gemmb64(hipStream_t s, const ushort*A,const ushort*Bt,float*C,ushort*Cb,int M,int N,int K,int act){
  int nbx = (N+127)/128;
  int nwg = nbx * (M/64);
  hipLaunchKernelGGL(gemm_bf16_64,dim3(nwg),dim3(256),0,s,A,Bt,C,Cb,M,N,K,act,nbx);
}

extern "C" void kernel_launch(void* const* d_in, const int* in_sizes, int n_in,
                              void* d_out, int out_size, void* d_ws, size_t ws_size,
                              hipStream_t stream) {
  const float* x        = (const float*)d_in[0];
  const float* norm_w   = (const float*)d_in[1];
  const float* in_proj_w= (const float*)d_in[2];
  const float* conv_w   = (const float*)d_in[3];
  const float* conv_b   = (const float*)d_in[4];
  const float* dt_bias  = (const float*)d_in[5];
  const float* A_log    = (const float*)d_in[6];
  const float* Dp       = (const float*)d_in[7];
  const float* ssm_norm_w=(const float*)d_in[8];
  const float* out_proj_w=(const float*)d_in[9];
  const float* scorer_w1= (const float*)d_in[10];
  const float* scorer_w2= (const float*)d_in[11];
  const float* summ_w   = (const float*)d_in[12];
  const float* q_w      = (const float*)d_in[13];
  const float* k_w      = (const float*)d_in[14];
  const float* v_w      = (const float*)d_in[15];
  const float* gate_w   = (const float*)d_in[16];
  float* out = (float*)d_out;

  unsigned char* base = (unsigned char*)d_ws;
  size_t off = 0;
  auto FB = [&](size_t bytes)->void*{ void* p = base+off; off = (off+bytes+255)&~(size_t)255; return p; };
  float* zxb   = (float*)FB((size_t)2048*D_IN_PROJ*4);
  float* dtb   = (float*)FB((size_t)2048*32*4);
  float* xbc   = (float*)FB((size_t)2048*CONV_DIM*4);
  float* csb   = (float*)FB((size_t)256*256*4);
  float* sdA   = (float*)FB(1024);
  float* states= (float*)FB((size_t)256*8192*4);
  float* prevb = (float*)FB((size_t)256*8192*4);
  float* ybuf  = (float*)FB((size_t)2048*2048*4);
  float* yout  = (float*)FB((size_t)2048*1024*4);
  float* scores= (float*)FB(2048*4);
  float* summ  = (float*)FB((size_t)2048*64*4);
  float* qb    = (float*)FB((size_t)2048*64*4);
  float* poolb = (float*)FB(POOL_N*64*4);
  float* prios = (float*)FB(256);
  float* miscf = (float*)FB(256);
  int*   counti= (int*)FB(256);
  int*   winners=(int*)FB(256);
  unsigned char* RX = (unsigned char*)FB((size_t)4194304);
  unsigned char* W1 = (unsigned char*)FB((size_t)8978432);

  ushort* xnb   = (ushort*)RX;
  ushort* scsqT = (ushort*)RX;                  // [384][1024] bf16
  float*  hsq   = (float*) (RX + 786432);       // [2048][384] f32
  float*  kkT   = (float*) ((unsigned char*)qb + 262144);
  ushort* vvT   = (ushort*)summ;
  ushort* Pb    = (ushort*)qb;
  ushort* inT   = (ushort*)W1;
  ushort* outT  = (ushort*)W1;
  ushort* gateT = (ushort*)(W1 + 4194304);
  float*  Gt    = yout;
  ushort* ybf   = (ushort*)prevb;
  float*  retr  = states;
  ushort* retrb = (ushort*)ybuf;
  ushort* youtb = (ushort*)((unsigned char*)ybuf + 8388608);
  (void)prios; (void)winners;

  // prep: in_proj weight transpose + rmsnorm in one launch
  k_prep<<<6432,256,0,stream>>>(in_proj_w, inT, x, norm_w, xnb);
  gemmb(stream, xnb, inT, zxb, nullptr, 2048, D_IN_PROJ, 1024, 0);
  // merged weight transposes (W1/RX phase-1 contents now dead)
  hipLaunchKernelGGL(k_transpose5, dim3(4480), dim3(256), 0, stream,
                     out_proj_w, outT, gate_w, gateT, scorer_w1, scsqT,
                     summ_w, scsqT + 256*1024, q_w, scsqT + 320*1024);
  k_conv4<<<4864,256,0,stream>>>(zxb, conv_w, conv_b, xbc, dt_bias, dtb);
  k_gt<<<2048,256,0,stream>>>(xbc, Gt);
  k_ssd1w<<<256,512,0,stream>>>(xbc, dtb, A_log, Gt, ybuf, states, csb, sdA);
  k_ssd2<<<2048,256,0,stream>>>(states, sdA, prevb);
  k_ssd3m<<<256,256,0,stream>>>(xbc, csb, prevb, Dp, ybuf);
  k_gate_norm<<<2048,256,0,stream>>>(ybuf, zxb, ssm_norm_w, ybf);
  gemmb64(stream, ybf, outT, yout, youtb, 2048, 1024, 2048, 0);
  gemmb64(stream, youtb, scsqT, hsq, nullptr, 2048, 384, 1024, 0);
  k_scorer2<<<2048,64,0,stream>>>(hsq, scorer_w2, scores);
  k_pool<<<1,64,0,stream>>>(scores, counti, miscf, hsq, poolb);
  k_kkvv<<<269,256,0,stream>>>(poolb, k_w, kkT, v_w, vvT);
  k_probs<<<512,256,0,stream>>>(hsq, kkT, counti, Pb);
  k_pv<<<128,256,0,stream>>>(Pb, vvT, retr, retrb);
  hipLaunchKernelGGL(gemm_gate64, dim3(256), dim3(256), 0, stream,
                     youtb, retrb, gateT, x, yout, retr, miscf, out);
  (void)in_sizes; (void)n_in; (void)out_size; (void)ws_size;
}